// Round 4
// baseline (984.986 us; speedup 1.0000x reference)
//
#include <hip/hip_runtime.h>
#include <hip/hip_bf16.h>

// ---------- types / helpers ----------
typedef unsigned short u16;
typedef __bf16  bf16x8 __attribute__((ext_vector_type(8)));
typedef float   f32x4  __attribute__((ext_vector_type(4)));
typedef unsigned int   u32x4 __attribute__((ext_vector_type(4)));
typedef unsigned short u16x4 __attribute__((ext_vector_type(4)));

union FragU { bf16x8 v; u16 u[8]; u32x4 q; };

__device__ __forceinline__ float b2f(u16 u) {
    unsigned int x = ((unsigned int)u) << 16;
    return __builtin_bit_cast(float, x);
}
__device__ __forceinline__ u16 f2b(float f) {
    unsigned int x = __builtin_bit_cast(unsigned int, f);
    unsigned int r = (x + 0x7fffu + ((x >> 16) & 1u)) >> 16;
    return (u16)r;
}
__device__ __forceinline__ float rcp_(float x) { return __builtin_amdgcn_rcpf(x); }
__device__ __forceinline__ float sigm_(float x) { return rcp_(1.0f + __expf(-x)); }
__device__ __forceinline__ float tanh_(float x) {
    float e = __expf(2.0f * x);
    return 1.0f - 2.0f * rcp_(e + 1.0f);
}
__device__ __forceinline__ bf16x8 load_afrag(const u16* s) {
    FragU f; f.q = *(const u32x4*)s; return f.v;
}
__device__ __forceinline__ f32x4 mfma16(bf16x8 a, bf16x8 b, f32x4 c) {
    return __builtin_amdgcn_mfma_f32_16x16x32_bf16(a, b, c, 0, 0, 0);
}
// split helper: hi bf16 + residual lo bf16
__device__ __forceinline__ void split2(float f, u16& hi, u16& lo) {
    hi = f2b(f); lo = f2b(f - b2f(hi));
}

// ---------------------------------------------------------------------------
// Split-bf16 GEMM body (effective-fp32): out = A @ W + bias (3 MFMAs/product)
// MODE 0: vocab-enc  A[256,128] = src_emb,      out xpv fp32 [256,192]
// MODE 1: vocab-dec  A[256,64]  = out_W^T * 8,  out xpv fp32 [256,192]
// MODE 2: enc_proj   A = fwd+bwd (4 bf16 planes), K=64,N=64,
//         out bf16 TRANSPOSED encpT[(b*64+col)*32+s] = (acc+be)*2
// MODE 3: logits     A = hid hi/lo planes, K=64,N=256, out fp32 d_out
// 256 thr, 64 rows; wave w covers cols [w*N/4,(w+1)*N/4)
// ---------------------------------------------------------------------------
template<int MODE, int K, int N>
__device__ __forceinline__ void gemm_body(
    const float* __restrict__ srcf, const u16* __restrict__ sh,
    const u16* __restrict__ sl, const u16* __restrict__ sh2,
    const u16* __restrict__ sl2, const float* __restrict__ W,
    const float* __restrict__ bias, float* __restrict__ outf,
    u16* __restrict__ outh, int rbase)
{
    constexpr int KP = K + 8;
    constexpr int LK = (K == 128) ? 7 : 6;
    __shared__ __attribute__((aligned(16))) u16 Ash[64 * KP];
    __shared__ __attribute__((aligned(16))) u16 Asl[64 * KP];

    const int tid  = threadIdx.x;
    const int lane = tid & 63, w = tid >> 6;
    const int q = lane >> 4, ln = lane & 15;

    // ---- stage A rows into LDS hi/lo ----
    for (int i = tid; i < 64 * K; i += 256) {
        int r = i >> LK, c = i & (K - 1);
        int rg = rbase + r;
        float f;
        if constexpr (MODE == 0)      f = srcf[rg * K + c];
        else if constexpr (MODE == 1) f = srcf[c * 256 + rg] * 8.0f;
        else if constexpr (MODE == 2)
            f = b2f(sh[rg * 64 + c]) + b2f(sl[rg * 64 + c])
              + b2f(sh2[rg * 64 + c]) + b2f(sl2[rg * 64 + c]);
        else                          f = b2f(sh[rg * 64 + c]) + b2f(sl[rg * 64 + c]);
        u16 hi, lo; split2(f, hi, lo);
        Ash[r * KP + c] = hi; Asl[r * KP + c] = lo;
    }

    // ---- B fragments hi/lo in registers ----
    constexpr int NT  = N / 64;
    constexpr int NKF = K / 32;
    FragU bfh[NT][NKF], bfl[NT][NKF];
    float bv[NT];
    const int cw = w * (N >> 2);
#pragma unroll
    for (int tl = 0; tl < NT; ++tl) {
        int col = cw + tl * 16 + ln;
#pragma unroll
        for (int kf = 0; kf < NKF; ++kf)
#pragma unroll
            for (int j = 0; j < 8; ++j) {
                float f = W[(kf * 32 + q * 8 + j) * N + col];
                split2(f, bfh[tl][kf].u[j], bfl[tl][kf].u[j]);
            }
        bv[tl] = bias[col];
    }
    __syncthreads();

#pragma unroll
    for (int r = 0; r < 4; ++r) {
        bf16x8 afh[NKF], afl[NKF];
#pragma unroll
        for (int kf = 0; kf < NKF; ++kf) {
            afh[kf] = load_afrag(&Ash[(r * 16 + ln) * KP + kf * 32 + q * 8]);
            afl[kf] = load_afrag(&Asl[(r * 16 + ln) * KP + kf * 32 + q * 8]);
        }
#pragma unroll
        for (int tl = 0; tl < NT; ++tl) {
            f32x4 acc = {0.f, 0.f, 0.f, 0.f};
#pragma unroll
            for (int kf = 0; kf < NKF; ++kf) {
                acc = mfma16(afl[kf], bfh[tl][kf].v, acc);
                acc = mfma16(afh[kf], bfl[tl][kf].v, acc);
                acc = mfma16(afh[kf], bfh[tl][kf].v, acc);
            }
            const int col = cw + tl * 16 + ln;
#pragma unroll
            for (int i = 0; i < 4; ++i) {
                int rowg = rbase + r * 16 + q * 4 + i;
                float val = acc[i] + bv[tl];
                if constexpr (MODE == 2) {
                    int b = rowg >> 5, s2 = rowg & 31;
                    outh[(b * 64 + col) * 32 + s2] = f2b(val * 2.0f);
                } else if constexpr (MODE == 3) {
                    outf[rowg * N + col] = val;
                } else {
                    outf[rowg * 192 + col] = val;
                }
            }
        }
    }
}

template<int MODE, int K, int N>
__global__ __launch_bounds__(256, (MODE >= 2) ? 2 : 1) void gemm_hl(
    const float* __restrict__ srcf, const u16* __restrict__ sh,
    const u16* __restrict__ sl, const u16* __restrict__ sh2,
    const u16* __restrict__ sl2, const float* __restrict__ W,
    const float* __restrict__ bias, float* __restrict__ outf,
    u16* __restrict__ outh)
{
    gemm_body<MODE, K, N>(srcf, sh, sl, sh2, sl2, W, bias, outf, outh,
                          (int)blockIdx.x * 64);
}

// All three tiny vocab-table GEMMs in ONE launch (12 blocks): blocks 0-3
// xpv_f, 4-7 xpv_b, 8-11 xpvd. Removes 2 serial dispatch gaps.
__global__ __launch_bounds__(256, 1) void xpv_all(
    const float* __restrict__ src_emb,
    const float* __restrict__ Wf, const float* __restrict__ bf, float* __restrict__ xf,
    const float* __restrict__ Wb, const float* __restrict__ bb, float* __restrict__ xb,
    const float* __restrict__ outW, const float* __restrict__ dW,
    const float* __restrict__ db, float* __restrict__ xd)
{
    const int b = blockIdx.x;
    if (b < 4)
        gemm_body<0, 128, 192>(src_emb, nullptr, nullptr, nullptr, nullptr,
                               Wf, bf, xf, nullptr, b * 64);
    else if (b < 8)
        gemm_body<0, 128, 192>(src_emb, nullptr, nullptr, nullptr, nullptr,
                               Wb, bb, xb, nullptr, (b - 4) * 64);
    else
        gemm_body<1, 64, 192>(outW, nullptr, nullptr, nullptr, nullptr,
                              dW, db, xd, nullptr, (b - 8) * 64);
}

// ---------------------------------------------------------------------------
// Fused bidirectional encoder GRU (split-bf16), 8 rows/block, 1024 blocks
// (blocks [0,512) = forward, [512,1024) = backward). Backward writes its own
// planes (bh/bl); fwd+bwd sum is folded into the MODE-2 gemm / dec staging.
// MFMA batch rows 8..15 are zero padding; writes guarded to q<2.
// ---------------------------------------------------------------------------
__global__ __launch_bounds__(256, 2) void enc8(
    const int* __restrict__ src_ids, const float* __restrict__ xf,
    const float* __restrict__ xb,
    const float* __restrict__ Uf_, const float* __restrict__ bf_,
    const float* __restrict__ Ub_, const float* __restrict__ bb_,
    u16* __restrict__ fh, u16* __restrict__ fl,
    u16* __restrict__ bh, u16* __restrict__ bl)
{
    __shared__ __attribute__((aligned(16))) u16 hsh[16 * 72];
    __shared__ __attribute__((aligned(16))) u16 hsl[16 * 72];
    const int tid  = threadIdx.x;
    const int lane = tid & 63, w = tid >> 6;
    const int q = lane >> 4, ln = lane & 15;
    const int dir = (int)(blockIdx.x >> 9);
    const int b0  = (int)(blockIdx.x & 511) * 8;
    const float* xpv = dir ? xb  : xf;
    const float* U   = dir ? Ub_ : Uf_;
    const float* b_  = dir ? bb_ : bf_;
    u16* oh = dir ? bh : fh;
    u16* ol = dir ? bl : fl;
    const int jw = w * 16;
    const bool rowok = (q < 2);

    for (int i = tid; i < 16 * 64; i += 256) {
        int r = i >> 6, c = i & 63;
        hsh[r * 72 + c] = 0; hsl[r * 72 + c] = 0;
    }
    FragU ufh[3][2], ufl[3][2];
    float b1[3];
#pragma unroll
    for (int g = 0; g < 3; ++g) {
        int col = g * 64 + jw + ln;
#pragma unroll
        for (int kf = 0; kf < 2; ++kf)
#pragma unroll
            for (int j = 0; j < 8; ++j) {
                float f = U[(kf * 32 + q * 8 + j) * 192 + col];
                split2(f, ufh[g][kf].u[j], ufl[g][kf].u[j]);
            }
        b1[g] = b_[192 + col];
    }
    float hp[4] = {0, 0, 0, 0};

    // prefetch x-gates for first step (rows clamped in-bounds for pad lanes)
    float xg[3][4];
    {
        const int s0 = dir ? 31 : 0;
#pragma unroll
        for (int i = 0; i < 4; ++i) {
            int rowv = b0 + ((q * 4 + i) & 7);
            int id = src_ids[rowv * 32 + s0];
#pragma unroll
            for (int g = 0; g < 3; ++g) xg[g][i] = xpv[id * 192 + g * 64 + jw + ln];
        }
    }
    __syncthreads();

    for (int step = 0; step < 32; ++step) {
        const int s = dir ? (31 - step) : step;
        // prefetch next step's x-gates
        float xgn[3][4];
        {
            int sn = dir ? (step >= 31 ? 0 : 30 - step) : (step >= 31 ? 31 : step + 1);
#pragma unroll
            for (int i = 0; i < 4; ++i) {
                int rowv = b0 + ((q * 4 + i) & 7);
                int id = src_ids[rowv * 32 + sn];
#pragma unroll
                for (int g = 0; g < 3; ++g) xgn[g][i] = xpv[id * 192 + g * 64 + jw + ln];
            }
        }
        bf16x8 a0h = load_afrag(&hsh[ln * 72 + q * 8]);
        bf16x8 a1h = load_afrag(&hsh[ln * 72 + 32 + q * 8]);
        bf16x8 a0l = load_afrag(&hsl[ln * 72 + q * 8]);
        bf16x8 a1l = load_afrag(&hsl[ln * 72 + 32 + q * 8]);
        f32x4 acc[3];
#pragma unroll
        for (int g = 0; g < 3; ++g) {
            f32x4 a = {0.f, 0.f, 0.f, 0.f};
            a = mfma16(a0l, ufh[g][0].v, a);
            a = mfma16(a0h, ufl[g][0].v, a);
            a = mfma16(a0h, ufh[g][0].v, a);
            a = mfma16(a1l, ufh[g][1].v, a);
            a = mfma16(a1h, ufl[g][1].v, a);
            a = mfma16(a1h, ufh[g][1].v, a);
            acc[g] = a;
        }
        float nh[4];
#pragma unroll
        for (int i = 0; i < 4; ++i) {
            const int rowg = b0 + q * 4 + i;
            float zz = sigm_(xg[0][i] + acc[0][i] + b1[0]);
            float rr = sigm_(xg[1][i] + acc[1][i] + b1[1]);
            float nn = tanh_(xg[2][i] + rr * (acc[2][i] + b1[2]));
            nh[i] = zz * hp[i] + (1.0f - zz) * nn;  hp[i] = nh[i];
            if (rowok) {
                const int gidx = (rowg * 32 + s) * 64 + jw + ln;
                u16 hi, lo; split2(nh[i], hi, lo);
                oh[gidx] = hi; ol[gidx] = lo;
            }
        }
        __syncthreads();
        if (rowok) {
#pragma unroll
            for (int i = 0; i < 4; ++i) {
                u16 hi, lo; split2(nh[i], hi, lo);
                hsh[(q * 4 + i) * 72 + jw + ln] = hi;
                hsl[(q * 4 + i) * 72 + jw + ln] = lo;
            }
        }
        __syncthreads();
#pragma unroll
        for (int g = 0; g < 3; ++g)
#pragma unroll
            for (int i = 0; i < 4; ++i) xg[g][i] = xgn[g][i];
    }
}

// ---------------------------------------------------------------------------
// Decoder: Bahdanau attention + GRU, split-bf16.
// 512 threads/block, 16 rows = TWO independent 8-row halves (threads 0-255 =
// half 0, 256-511 = half 1), each with private LDS buffers. A single 8-wave
// workgroup is guaranteed fully resident -> 2 waves/SIMD latency hiding
// WITHOUT betting on inter-block co-residency (which failed in R3: 2x78.8KiB
// blocks never co-scheduled; occupancy stayed 11.6%). Grid 256 = 1 block/CU.
// LDS total ~153 KiB <= 160 KiB.
// ---------------------------------------------------------------------------
__global__ __launch_bounds__(512, 2) void dec_kernel(
    const int* __restrict__ tgt_ids, const float* __restrict__ xpvd,
    const u16* __restrict__ fh, const u16* __restrict__ fl,
    const u16* __restrict__ bh, const u16* __restrict__ bl,
    const u16* __restrict__ encpT,
    const float* __restrict__ dec_U, const float* __restrict__ dec_W,
    const float* __restrict__ dec_b,
    const float* __restrict__ Wd, const float* __restrict__ bd,
    const float* __restrict__ v_, const float* __restrict__ bv_,
    u16* __restrict__ hid_hi, u16* __restrict__ hid_lo)
{
    __shared__ __attribute__((aligned(16))) float enc_lds[2][8 * 2048]; // 128 KiB
    __shared__ __attribute__((aligned(16))) u16 hqh[2][16 * 72];
    __shared__ __attribute__((aligned(16))) u16 hql[2][16 * 72];
    __shared__ __attribute__((aligned(16))) u16 cxh[2][16 * 72];
    __shared__ __attribute__((aligned(16))) u16 cxl[2][16 * 72];
    __shared__ __attribute__((aligned(16))) float edl[2][8 * 72];      // exp(2*dproj)
    __shared__ float wl[2][8 * 36];
    __shared__ float vl[64];
    const int tid  = threadIdx.x;
    const int t2   = tid & 255;          // index within half
    const int half = tid >> 8;
    const int lane = t2 & 63, w = t2 >> 6;
    const int q = lane >> 4, ln = lane & 15;
    const int b0 = blockIdx.x * 16 + half * 8;
    const int jw = w * 16;
    const bool rowok = (q < 2);

    float* encL = enc_lds[half];
    u16*  hqhL = hqh[half];  u16* hqlL = hql[half];
    u16*  cxhL = cxh[half];  u16* cxlL = cxl[half];
    float* edlL = edl[half]; float* wlL = wl[half];

    // ---- stage encoded = fwd_hi+fwd_lo+bwd_hi+bwd_lo (fp32) into LDS ----
    {
        const u16* g0 = fh + (size_t)b0 * 2048;
        const u16* g1 = fl + (size_t)b0 * 2048;
        const u16* g2 = bh + (size_t)b0 * 2048;
        const u16* g3 = bl + (size_t)b0 * 2048;
        for (int i = t2; i < 8 * 2048 / 4; i += 256) {
            u16x4 v0 = *(const u16x4*)(g0 + i * 4);
            u16x4 v1 = *(const u16x4*)(g1 + i * 4);
            u16x4 v2 = *(const u16x4*)(g2 + i * 4);
            u16x4 v3 = *(const u16x4*)(g3 + i * 4);
            f32x4 f;
#pragma unroll
            for (int k = 0; k < 4; ++k)
                f[k] = (b2f(v0[k]) + b2f(v1[k])) + (b2f(v2[k]) + b2f(v3[k]));
            *(f32x4*)(&encL[i * 4]) = f;
        }
    }
    if (tid < 64) vl[tid] = v_[tid];
    const float bv0 = bv_[0];

    FragU wdh[2], wdl[2], ufh[3][2], ufl[3][2], wch[3][2], wcl[3][2];
    float b1[3];
#pragma unroll
    for (int kf = 0; kf < 2; ++kf)
#pragma unroll
        for (int j = 0; j < 8; ++j) {
            float f = Wd[(kf * 32 + q * 8 + j) * 64 + jw + ln];
            split2(f, wdh[kf].u[j], wdl[kf].u[j]);
        }
#pragma unroll
    for (int g = 0; g < 3; ++g) {
        int col = g * 64 + jw + ln;
#pragma unroll
        for (int kf = 0; kf < 2; ++kf)
#pragma unroll
            for (int j = 0; j < 8; ++j) {
                int k = kf * 32 + q * 8 + j;
                float fu = dec_U[k * 192 + col];
                split2(fu, ufh[g][kf].u[j], ufl[g][kf].u[j]);
                float fc = dec_W[(64 + k) * 192 + col];
                split2(fc, wch[g][kf].u[j], wcl[g][kf].u[j]);
            }
        b1[g] = dec_b[192 + col];
    }
    const float bd_ = bd[jw + ln];

    // ---- step-invariant exp(2e) cache in VGPRs: this thread's (b,s) pair ----
    float Ee[64];
    {
        const int bb2 = t2 >> 5, ss = t2 & 31;
        const u16* ep = &encpT[(size_t)(b0 + bb2) * 2048 + ss];
#pragma unroll
        for (int a = 0; a < 64; ++a) Ee[a] = __expf(b2f(ep[a * 32]));
    }

    // prefetch t=0 x-gates (BOW = 1 for all rows)
    float xg[3][4];
#pragma unroll
    for (int g = 0; g < 3; ++g) {
        float f = xpvd[1 * 192 + g * 64 + jw + ln];
#pragma unroll
        for (int i = 0; i < 4; ++i) xg[g][i] = f;
    }
    __syncthreads();   // enc_lds + vl ready

    // SVB = bias_v + sum_a v[a]   (logit = SVB - 2 * sum_a v[a]/(E+1))
    float SVB = bv0;
#pragma unroll
    for (int a = 0; a < 64; ++a) SVB += vl[a];

    // h0 = encoded[:,0]; zero-pad rows 8..15 of h and ctx tiles
    for (int i = t2; i < 16 * 64; i += 256) {
        int r = i >> 6, c = i & 63;
        if (r < 8) {
            u16 hi, lo; split2(encL[r * 2048 + c], hi, lo);
            hqhL[r * 72 + c] = hi; hqlL[r * 72 + c] = lo;
        } else {
            hqhL[r * 72 + c] = 0; hqlL[r * 72 + c] = 0;
            cxhL[r * 72 + c] = 0; cxlL[r * 72 + c] = 0;
        }
    }
    float hp[4];
#pragma unroll
    for (int i = 0; i < 4; ++i)
        hp[i] = rowok ? encL[(q * 4 + i) * 2048 + jw + ln] : 0.f;
    __syncthreads();

    for (int t = 0; t < 32; ++t) {
        // prefetch next step's x-gates: dec_in[t+1] = tgt[t]
        float xgn[3][4];
        {
            int tn = (t >= 31) ? 30 : t;
#pragma unroll
            for (int i = 0; i < 4; ++i) {
                int rowv = b0 + ((q * 4 + i) & 7);
                int id = tgt_ids[rowv * 32 + tn];
#pragma unroll
                for (int g = 0; g < 3; ++g) xgn[g][i] = xpvd[id * 192 + g * 64 + jw + ln];
            }
        }
        bf16x8 ah0 = load_afrag(&hqhL[ln * 72 + q * 8]);
        bf16x8 ah1 = load_afrag(&hqhL[ln * 72 + 32 + q * 8]);
        bf16x8 al0 = load_afrag(&hqlL[ln * 72 + q * 8]);
        bf16x8 al1 = load_afrag(&hqlL[ln * 72 + 32 + q * 8]);
        // edl = exp(2*(h@Wd + bd))
        {
            f32x4 a = {0.f, 0.f, 0.f, 0.f};
            a = mfma16(al0, wdh[0].v, a);
            a = mfma16(ah0, wdl[0].v, a);
            a = mfma16(ah0, wdh[0].v, a);
            a = mfma16(al1, wdh[1].v, a);
            a = mfma16(ah1, wdl[1].v, a);
            a = mfma16(ah1, wdh[1].v, a);
            if (rowok) {
#pragma unroll
                for (int i = 0; i < 4; ++i)
                    edlL[(q * 4 + i) * 72 + jw + ln] = __expf((a[i] + bd_) * 2.0f);
            }
        }
        __syncthreads();
        // scores + softmax over S: E = E_d * E_e; tanh = 1 - 2/(E+1)
        {
            const int bb2 = t2 >> 5, sidx = t2 & 31;
            const float* dp = &edlL[bb2 * 72];
            float av0 = 0.f, av1 = 0.f, av2 = 0.f, av3 = 0.f;
#pragma unroll
            for (int a4 = 0; a4 < 16; ++a4) {
                f32x4 dv = *(const f32x4*)(dp + a4 * 4);
                av0 += vl[a4 * 4 + 0] * rcp_(__builtin_fmaf(dv[0], Ee[a4 * 4 + 0], 1.0f));
                av1 += vl[a4 * 4 + 1] * rcp_(__builtin_fmaf(dv[1], Ee[a4 * 4 + 1], 1.0f));
                av2 += vl[a4 * 4 + 2] * rcp_(__builtin_fmaf(dv[2], Ee[a4 * 4 + 2], 1.0f));
                av3 += vl[a4 * 4 + 3] * rcp_(__builtin_fmaf(dv[3], Ee[a4 * 4 + 3], 1.0f));
            }
            float logit = SVB - 2.0f * ((av0 + av1) + (av2 + av3));
            float m = logit;
#pragma unroll
            for (int off = 16; off > 0; off >>= 1) m = fmaxf(m, __shfl_xor(m, off, 32));
            float e2 = __expf(logit - m);
            float ssum = e2;
#pragma unroll
            for (int off = 16; off > 0; off >>= 1) ssum += __shfl_xor(ssum, off, 32);
            wlL[bb2 * 36 + sidx] = e2 * rcp_(ssum);
        }
        __syncthreads();
        // ctx = sum_s w[s] * encoded[b,s,:]  — LDS-only, wave-per-row sweep
#pragma unroll
        for (int rr2 = 0; rr2 < 2; ++rr2) {
            const int b = rr2 * 4 + w;
            float c0 = 0.f, c1 = 0.f, c2 = 0.f, c3 = 0.f;
#pragma unroll
            for (int s4 = 0; s4 < 8; ++s4) {
                const int s = s4 * 4 + q;
                const float ww = wlL[b * 36 + s];
                f32x4 ev = *(const f32x4*)(&encL[b * 2048 + s * 64 + ln * 4]);
                c0 += ww * ev[0]; c1 += ww * ev[1];
                c2 += ww * ev[2]; c3 += ww * ev[3];
            }
            c0 += __shfl_xor(c0, 16); c0 += __shfl_xor(c0, 32);
            c1 += __shfl_xor(c1, 16); c1 += __shfl_xor(c1, 32);
            c2 += __shfl_xor(c2, 16); c2 += __shfl_xor(c2, 32);
            c3 += __shfl_xor(c3, 16); c3 += __shfl_xor(c3, 32);
            if (q == 0) {
                u16x4 vh, vo;
                u16 th, tl2;
                split2(c0, th, tl2); vh[0] = th; vo[0] = tl2;
                split2(c1, th, tl2); vh[1] = th; vo[1] = tl2;
                split2(c2, th, tl2); vh[2] = th; vo[2] = tl2;
                split2(c3, th, tl2); vh[3] = th; vo[3] = tl2;
                *(u16x4*)(&cxhL[b * 72 + ln * 4]) = vh;
                *(u16x4*)(&cxlL[b * 72 + ln * 4]) = vo;
            }
        }
        __syncthreads();
        // GRU gates: ax[g] = ctx@Wc (input path), ahh[g] = h@U (recurrent)
        bf16x8 ac0 = load_afrag(&cxhL[ln * 72 + q * 8]);
        bf16x8 ac1 = load_afrag(&cxhL[ln * 72 + 32 + q * 8]);
        bf16x8 al2 = load_afrag(&cxlL[ln * 72 + q * 8]);
        bf16x8 al3 = load_afrag(&cxlL[ln * 72 + 32 + q * 8]);
        f32x4 ax[3], ahh[3];
#pragma unroll
        for (int g = 0; g < 3; ++g) {
            f32x4 a = {0.f, 0.f, 0.f, 0.f};
            a = mfma16(al2, wch[g][0].v, a);
            a = mfma16(ac0, wcl[g][0].v, a);
            a = mfma16(ac0, wch[g][0].v, a);
            a = mfma16(al3, wch[g][1].v, a);
            a = mfma16(ac1, wcl[g][1].v, a);
            a = mfma16(ac1, wch[g][1].v, a);
            ax[g] = a;
            f32x4 h = {0.f, 0.f, 0.f, 0.f};
            h = mfma16(al0, ufh[g][0].v, h);
            h = mfma16(ah0, ufl[g][0].v, h);
            h = mfma16(ah0, ufh[g][0].v, h);
            h = mfma16(al1, ufh[g][1].v, h);
            h = mfma16(ah1, ufl[g][1].v, h);
            h = mfma16(ah1, ufh[g][1].v, h);
            ahh[g] = h;
        }
        float nh[4];
#pragma unroll
        for (int i = 0; i < 4; ++i) {
            int rowg = b0 + q * 4 + i;
            float zz = sigm_(xg[0][i] + ax[0][i] + ahh[0][i] + b1[0]);
            float rr = sigm_(xg[1][i] + ax[1][i] + ahh[1][i] + b1[1]);
            float nn = tanh_(xg[2][i] + ax[2][i] + rr * (ahh[2][i] + b1[2]));
            nh[i] = zz * hp[i] + (1.0f - zz) * nn;  hp[i] = nh[i];
            if (rowok) {
                int gidx = (rowg * 32 + t) * 64 + jw + ln;
                u16 hi, lo; split2(nh[i], hi, lo);
                hid_hi[gidx] = hi; hid_lo[gidx] = lo;
                hqhL[(q * 4 + i) * 72 + jw + ln] = hi;
                hqlL[(q * 4 + i) * 72 + jw + ln] = lo;
            }
        }
        // h-tile writes ordered for step t+1 by the barrier below.
        __syncthreads();
#pragma unroll
        for (int g = 0; g < 3; ++g)
#pragma unroll
            for (int i = 0; i < 4; ++i) xg[g][i] = xgn[g][i];
    }
}

// ---------------------------------------------------------------------------
extern "C" void kernel_launch(void* const* d_in, const int* in_sizes, int n_in,
                              void* d_out, int out_size, void* d_ws, size_t ws_size,
                              hipStream_t stream) {
    const int*   src_ids = (const int*)d_in[0];
    const int*   tgt_ids = (const int*)d_in[1];
    const float* src_emb = (const float*)d_in[2];
    const float* enc_Wf  = (const float*)d_in[3];
    const float* enc_Uf  = (const float*)d_in[4];
    const float* enc_bf  = (const float*)d_in[5];
    const float* enc_Wb  = (const float*)d_in[6];
    const float* enc_Ub  = (const float*)d_in[7];
    const float* enc_bb  = (const float*)d_in[8];
    const float* attn_We = (const float*)d_in[9];
    const float* attn_be = (const float*)d_in[10];
    const float* attn_Wd = (const float*)d_in[11];
    const float* attn_bd = (const float*)d_in[12];
    const float* attn_v  = (const float*)d_in[13];
    const float* attn_bv = (const float*)d_in[14];
    const float* dec_W   = (const float*)d_in[15];
    const float* dec_U   = (const float*)d_in[16];
    const float* dec_b   = (const float*)d_in[17];
    const float* out_W   = (const float*)d_in[18];
    const float* out_b   = (const float*)d_in[19];

    // ws layout (u16 units). fwd [0,16)/[16,32) MiB, bwd [32,48)/[48,64),
    // encpT [64,80), xpv_f/xpv_b/xpvd after 80 MiB. hid reuses fwd planes
    // (dec reads its own rows before overwriting them).
    u16* ws = (u16*)d_ws;
    u16* fwd_hi = ws;
    u16* fwd_lo = ws +  8388608;
    u16* bwd_hi = ws + 16777216;
    u16* bwd_lo = ws + 25165824;
    u16* encpT  = ws + 33554432;
    float* xpv_f = (float*)(ws + 41943040);
    float* xpv_b = (float*)(ws + 42041344);
    float* xpvd  = (float*)(ws + 42139648);
    u16* hid_hi = fwd_hi;
    u16* hid_lo = fwd_lo;

    dim3 blk(256);
    xpv_all<<<12, blk, 0, stream>>>(src_emb, enc_Wf, enc_bf, xpv_f,
                                    enc_Wb, enc_bb, xpv_b,
                                    out_W, dec_W, dec_b, xpvd);
    enc8<<<1024, blk, 0, stream>>>(src_ids, xpv_f, xpv_b, enc_Uf, enc_bf,
                                   enc_Ub, enc_bb, fwd_hi, fwd_lo, bwd_hi, bwd_lo);
    gemm_hl<2, 64, 64><<<2048, blk, 0, stream>>>(
        nullptr, fwd_hi, fwd_lo, bwd_hi, bwd_lo, attn_We, attn_be, nullptr, encpT);
    dec_kernel<<<256, dim3(512), 0, stream>>>(tgt_ids, xpvd, fwd_hi, fwd_lo,
                                              bwd_hi, bwd_lo, encpT,
                                              dec_U, dec_W, dec_b,
                                              attn_Wd, attn_bd, attn_v, attn_bv,
                                              hid_hi, hid_lo);
    gemm_hl<3, 64, 256><<<2048, blk, 0, stream>>>(
        nullptr, hid_hi, hid_lo, nullptr, nullptr, out_W, out_b, (float*)d_out, nullptr);
}

// Round 6
// 982.758 us; speedup vs baseline: 1.0023x; 1.0023x over previous
//
#include <hip/hip_runtime.h>
#include <hip/hip_bf16.h>

// ---------- types / helpers ----------
typedef unsigned short u16;
typedef __bf16  bf16x8 __attribute__((ext_vector_type(8)));
typedef float   f32x4  __attribute__((ext_vector_type(4)));
typedef unsigned int   u32x4 __attribute__((ext_vector_type(4)));
typedef unsigned short u16x4 __attribute__((ext_vector_type(4)));

union FragU { bf16x8 v; u16 u[8]; u32x4 q; };

__device__ __forceinline__ float b2f(u16 u) {
    unsigned int x = ((unsigned int)u) << 16;
    return __builtin_bit_cast(float, x);
}
__device__ __forceinline__ u16 f2b(float f) {
    unsigned int x = __builtin_bit_cast(unsigned int, f);
    unsigned int r = (x + 0x7fffu + ((x >> 16) & 1u)) >> 16;
    return (u16)r;
}
__device__ __forceinline__ float rcp_(float x) { return __builtin_amdgcn_rcpf(x); }
__device__ __forceinline__ float sigm_(float x) { return rcp_(1.0f + __expf(-x)); }
__device__ __forceinline__ float tanh_(float x) {
    float e = __expf(2.0f * x);
    return 1.0f - 2.0f * rcp_(e + 1.0f);
}
__device__ __forceinline__ bf16x8 load_afrag(const u16* s) {
    FragU f; f.q = *(const u32x4*)s; return f.v;
}
__device__ __forceinline__ f32x4 mfma16(bf16x8 a, bf16x8 b, f32x4 c) {
    return __builtin_amdgcn_mfma_f32_16x16x32_bf16(a, b, c, 0, 0, 0);
}
// split helper: hi bf16 + residual lo bf16
__device__ __forceinline__ void split2(float f, u16& hi, u16& lo) {
    hi = f2b(f); lo = f2b(f - b2f(hi));
}

// ---------------------------------------------------------------------------
// Split-bf16 GEMM body (effective-fp32): out = A @ W + bias (3 MFMAs/product)
// MODE 0: vocab-enc  A[256,128] = src_emb,      out xpv fp32 [256,192]
// MODE 1: vocab-dec  A[256,64]  = out_W^T * 8,  out xpv fp32 [256,192]
// MODE 2: enc_proj   A = fwd+bwd (4 bf16 planes), K=64,N=64,
//         out bf16 TRANSPOSED encpT[(b*64+col)*32+s] = (acc+be)*2
// MODE 3: logits     A = hid hi/lo planes, K=64,N=256, out fp32 d_out
// 256 thr, 64 rows; wave w covers cols [w*N/4,(w+1)*N/4)
// ---------------------------------------------------------------------------
template<int MODE, int K, int N>
__device__ __forceinline__ void gemm_body(
    const float* __restrict__ srcf, const u16* __restrict__ sh,
    const u16* __restrict__ sl, const u16* __restrict__ sh2,
    const u16* __restrict__ sl2, const float* __restrict__ W,
    const float* __restrict__ bias, float* __restrict__ outf,
    u16* __restrict__ outh, int rbase)
{
    constexpr int KP = K + 8;
    constexpr int LK = (K == 128) ? 7 : 6;
    __shared__ __attribute__((aligned(16))) u16 Ash[64 * KP];
    __shared__ __attribute__((aligned(16))) u16 Asl[64 * KP];

    const int tid  = threadIdx.x;
    const int lane = tid & 63, w = tid >> 6;
    const int q = lane >> 4, ln = lane & 15;

    // ---- stage A rows into LDS hi/lo ----
    for (int i = tid; i < 64 * K; i += 256) {
        int r = i >> LK, c = i & (K - 1);
        int rg = rbase + r;
        float f;
        if constexpr (MODE == 0)      f = srcf[rg * K + c];
        else if constexpr (MODE == 1) f = srcf[c * 256 + rg] * 8.0f;
        else if constexpr (MODE == 2)
            f = b2f(sh[rg * 64 + c]) + b2f(sl[rg * 64 + c])
              + b2f(sh2[rg * 64 + c]) + b2f(sl2[rg * 64 + c]);
        else                          f = b2f(sh[rg * 64 + c]) + b2f(sl[rg * 64 + c]);
        u16 hi, lo; split2(f, hi, lo);
        Ash[r * KP + c] = hi; Asl[r * KP + c] = lo;
    }

    // ---- B fragments hi/lo in registers ----
    constexpr int NT  = N / 64;
    constexpr int NKF = K / 32;
    FragU bfh[NT][NKF], bfl[NT][NKF];
    float bv[NT];
    const int cw = w * (N >> 2);
#pragma unroll
    for (int tl = 0; tl < NT; ++tl) {
        int col = cw + tl * 16 + ln;
#pragma unroll
        for (int kf = 0; kf < NKF; ++kf)
#pragma unroll
            for (int j = 0; j < 8; ++j) {
                float f = W[(kf * 32 + q * 8 + j) * N + col];
                split2(f, bfh[tl][kf].u[j], bfl[tl][kf].u[j]);
            }
        bv[tl] = bias[col];
    }
    __syncthreads();

#pragma unroll
    for (int r = 0; r < 4; ++r) {
        bf16x8 afh[NKF], afl[NKF];
#pragma unroll
        for (int kf = 0; kf < NKF; ++kf) {
            afh[kf] = load_afrag(&Ash[(r * 16 + ln) * KP + kf * 32 + q * 8]);
            afl[kf] = load_afrag(&Asl[(r * 16 + ln) * KP + kf * 32 + q * 8]);
        }
#pragma unroll
        for (int tl = 0; tl < NT; ++tl) {
            f32x4 acc = {0.f, 0.f, 0.f, 0.f};
#pragma unroll
            for (int kf = 0; kf < NKF; ++kf) {
                acc = mfma16(afl[kf], bfh[tl][kf].v, acc);
                acc = mfma16(afh[kf], bfl[tl][kf].v, acc);
                acc = mfma16(afh[kf], bfh[tl][kf].v, acc);
            }
            const int col = cw + tl * 16 + ln;
#pragma unroll
            for (int i = 0; i < 4; ++i) {
                int rowg = rbase + r * 16 + q * 4 + i;
                float val = acc[i] + bv[tl];
                if constexpr (MODE == 2) {
                    int b = rowg >> 5, s2 = rowg & 31;
                    outh[(b * 64 + col) * 32 + s2] = f2b(val * 2.0f);
                } else if constexpr (MODE == 3) {
                    outf[rowg * N + col] = val;
                } else {
                    outf[rowg * 192 + col] = val;
                }
            }
        }
    }
}

template<int MODE, int K, int N>
__global__ __launch_bounds__(256, (MODE >= 2) ? 2 : 1) void gemm_hl(
    const float* __restrict__ srcf, const u16* __restrict__ sh,
    const u16* __restrict__ sl, const u16* __restrict__ sh2,
    const u16* __restrict__ sl2, const float* __restrict__ W,
    const float* __restrict__ bias, float* __restrict__ outf,
    u16* __restrict__ outh)
{
    gemm_body<MODE, K, N>(srcf, sh, sl, sh2, sl2, W, bias, outf, outh,
                          (int)blockIdx.x * 64);
}

// All three tiny vocab-table GEMMs in ONE launch (12 blocks): blocks 0-3
// xpv_f, 4-7 xpv_b, 8-11 xpvd. Removes 2 serial dispatch gaps.
__global__ __launch_bounds__(256, 1) void xpv_all(
    const float* __restrict__ src_emb,
    const float* __restrict__ Wf, const float* __restrict__ bf, float* __restrict__ xf,
    const float* __restrict__ Wb, const float* __restrict__ bb, float* __restrict__ xb,
    const float* __restrict__ outW, const float* __restrict__ dW,
    const float* __restrict__ db, float* __restrict__ xd)
{
    const int b = blockIdx.x;
    if (b < 4)
        gemm_body<0, 128, 192>(src_emb, nullptr, nullptr, nullptr, nullptr,
                               Wf, bf, xf, nullptr, b * 64);
    else if (b < 8)
        gemm_body<0, 128, 192>(src_emb, nullptr, nullptr, nullptr, nullptr,
                               Wb, bb, xb, nullptr, (b - 4) * 64);
    else
        gemm_body<1, 64, 192>(outW, nullptr, nullptr, nullptr, nullptr,
                              dW, db, xd, nullptr, (b - 8) * 64);
}

// ---------------------------------------------------------------------------
// Fused bidirectional encoder GRU (split-bf16), 8 rows/block, 1024 blocks
// (blocks [0,512) = forward, [512,1024) = backward). Backward writes its own
// planes (bh/bl); fwd+bwd sum is folded into the MODE-2 gemm / dec staging.
// MFMA batch rows 8..15 are zero padding; writes guarded to q<2.
// ---------------------------------------------------------------------------
__global__ __launch_bounds__(256, 2) void enc8(
    const int* __restrict__ src_ids, const float* __restrict__ xf,
    const float* __restrict__ xb,
    const float* __restrict__ Uf_, const float* __restrict__ bf_,
    const float* __restrict__ Ub_, const float* __restrict__ bb_,
    u16* __restrict__ fh, u16* __restrict__ fl,
    u16* __restrict__ bh, u16* __restrict__ bl)
{
    __shared__ __attribute__((aligned(16))) u16 hsh[16 * 72];
    __shared__ __attribute__((aligned(16))) u16 hsl[16 * 72];
    const int tid  = threadIdx.x;
    const int lane = tid & 63, w = tid >> 6;
    const int q = lane >> 4, ln = lane & 15;
    const int dir = (int)(blockIdx.x >> 9);
    const int b0  = (int)(blockIdx.x & 511) * 8;
    const float* xpv = dir ? xb  : xf;
    const float* U   = dir ? Ub_ : Uf_;
    const float* b_  = dir ? bb_ : bf_;
    u16* oh = dir ? bh : fh;
    u16* ol = dir ? bl : fl;
    const int jw = w * 16;
    const bool rowok = (q < 2);

    for (int i = tid; i < 16 * 64; i += 256) {
        int r = i >> 6, c = i & 63;
        hsh[r * 72 + c] = 0; hsl[r * 72 + c] = 0;
    }
    FragU ufh[3][2], ufl[3][2];
    float b1[3];
#pragma unroll
    for (int g = 0; g < 3; ++g) {
        int col = g * 64 + jw + ln;
#pragma unroll
        for (int kf = 0; kf < 2; ++kf)
#pragma unroll
            for (int j = 0; j < 8; ++j) {
                float f = U[(kf * 32 + q * 8 + j) * 192 + col];
                split2(f, ufh[g][kf].u[j], ufl[g][kf].u[j]);
            }
        b1[g] = b_[192 + col];
    }
    float hp[4] = {0, 0, 0, 0};

    // prefetch x-gates for first step (rows clamped in-bounds for pad lanes)
    float xg[3][4];
    {
        const int s0 = dir ? 31 : 0;
#pragma unroll
        for (int i = 0; i < 4; ++i) {
            int rowv = b0 + ((q * 4 + i) & 7);
            int id = src_ids[rowv * 32 + s0];
#pragma unroll
            for (int g = 0; g < 3; ++g) xg[g][i] = xpv[id * 192 + g * 64 + jw + ln];
        }
    }
    __syncthreads();

    for (int step = 0; step < 32; ++step) {
        const int s = dir ? (31 - step) : step;
        // prefetch next step's x-gates
        float xgn[3][4];
        {
            int sn = dir ? (step >= 31 ? 0 : 30 - step) : (step >= 31 ? 31 : step + 1);
#pragma unroll
            for (int i = 0; i < 4; ++i) {
                int rowv = b0 + ((q * 4 + i) & 7);
                int id = src_ids[rowv * 32 + sn];
#pragma unroll
                for (int g = 0; g < 3; ++g) xgn[g][i] = xpv[id * 192 + g * 64 + jw + ln];
            }
        }
        bf16x8 a0h = load_afrag(&hsh[ln * 72 + q * 8]);
        bf16x8 a1h = load_afrag(&hsh[ln * 72 + 32 + q * 8]);
        bf16x8 a0l = load_afrag(&hsl[ln * 72 + q * 8]);
        bf16x8 a1l = load_afrag(&hsl[ln * 72 + 32 + q * 8]);
        f32x4 acc[3];
#pragma unroll
        for (int g = 0; g < 3; ++g) {
            f32x4 a = {0.f, 0.f, 0.f, 0.f};
            a = mfma16(a0l, ufh[g][0].v, a);
            a = mfma16(a0h, ufl[g][0].v, a);
            a = mfma16(a0h, ufh[g][0].v, a);
            a = mfma16(a1l, ufh[g][1].v, a);
            a = mfma16(a1h, ufl[g][1].v, a);
            a = mfma16(a1h, ufh[g][1].v, a);
            acc[g] = a;
        }
        float nh[4];
#pragma unroll
        for (int i = 0; i < 4; ++i) {
            const int rowg = b0 + q * 4 + i;
            float zz = sigm_(xg[0][i] + acc[0][i] + b1[0]);
            float rr = sigm_(xg[1][i] + acc[1][i] + b1[1]);
            float nn = tanh_(xg[2][i] + rr * (acc[2][i] + b1[2]));
            nh[i] = zz * hp[i] + (1.0f - zz) * nn;  hp[i] = nh[i];
            if (rowok) {
                const int gidx = (rowg * 32 + s) * 64 + jw + ln;
                u16 hi, lo; split2(nh[i], hi, lo);
                oh[gidx] = hi; ol[gidx] = lo;
            }
        }
        __syncthreads();
        if (rowok) {
#pragma unroll
            for (int i = 0; i < 4; ++i) {
                u16 hi, lo; split2(nh[i], hi, lo);
                hsh[(q * 4 + i) * 72 + jw + ln] = hi;
                hsl[(q * 4 + i) * 72 + jw + ln] = lo;
            }
        }
        __syncthreads();
#pragma unroll
        for (int g = 0; g < 3; ++g)
#pragma unroll
            for (int i = 0; i < 4; ++i) xg[g][i] = xgn[g][i];
    }
}

// ---------------------------------------------------------------------------
// Decoder: Bahdanau attention + GRU, split-bf16.
// 512 threads/block, 16 rows = TWO independent 8-row halves (threads 0-255 =
// half 0, 256-511 = half 1), each with private LDS buffers. A single 8-wave
// workgroup is guaranteed fully resident -> 2 waves/SIMD latency hiding.
// launch_bounds(512, 1): KEEP THE REGISTER CAP OFF. (512,2) capped VGPRs at
// 128 and re-introduced the 578 MB scratch-spill regression (R4); the body
// needs ~176 VGPRs (R3). 2 waves/SIMD x 176 = 352 <= 512-reg pool, so the
// 8-wave block shape alone delivers the occupancy. LDS ~153 KiB <= 160 KiB.
// ---------------------------------------------------------------------------
__global__ __launch_bounds__(512, 1) void dec_kernel(
    const int* __restrict__ tgt_ids, const float* __restrict__ xpvd,
    const u16* __restrict__ fh, const u16* __restrict__ fl,
    const u16* __restrict__ bh, const u16* __restrict__ bl,
    const u16* __restrict__ encpT,
    const float* __restrict__ dec_U, const float* __restrict__ dec_W,
    const float* __restrict__ dec_b,
    const float* __restrict__ Wd, const float* __restrict__ bd,
    const float* __restrict__ v_, const float* __restrict__ bv_,
    u16* __restrict__ hid_hi, u16* __restrict__ hid_lo)
{
    __shared__ __attribute__((aligned(16))) float enc_lds[2][8 * 2048]; // 128 KiB
    __shared__ __attribute__((aligned(16))) u16 hqh[2][16 * 72];
    __shared__ __attribute__((aligned(16))) u16 hql[2][16 * 72];
    __shared__ __attribute__((aligned(16))) u16 cxh[2][16 * 72];
    __shared__ __attribute__((aligned(16))) u16 cxl[2][16 * 72];
    __shared__ __attribute__((aligned(16))) float edl[2][8 * 72];      // exp(2*dproj)
    __shared__ float wl[2][8 * 36];
    __shared__ float vl[64];
    const int tid  = threadIdx.x;
    const int t2   = tid & 255;          // index within half
    const int half = tid >> 8;
    const int lane = t2 & 63, w = t2 >> 6;
    const int q = lane >> 4, ln = lane & 15;
    const int b0 = blockIdx.x * 16 + half * 8;
    const int jw = w * 16;
    const bool rowok = (q < 2);

    float* encL = enc_lds[half];
    u16*  hqhL = hqh[half];  u16* hqlL = hql[half];
    u16*  cxhL = cxh[half];  u16* cxlL = cxl[half];
    float* edlL = edl[half]; float* wlL = wl[half];

    // ---- stage encoded = fwd_hi+fwd_lo+bwd_hi+bwd_lo (fp32) into LDS ----
    {
        const u16* g0 = fh + (size_t)b0 * 2048;
        const u16* g1 = fl + (size_t)b0 * 2048;
        const u16* g2 = bh + (size_t)b0 * 2048;
        const u16* g3 = bl + (size_t)b0 * 2048;
        for (int i = t2; i < 8 * 2048 / 4; i += 256) {
            u16x4 v0 = *(const u16x4*)(g0 + i * 4);
            u16x4 v1 = *(const u16x4*)(g1 + i * 4);
            u16x4 v2 = *(const u16x4*)(g2 + i * 4);
            u16x4 v3 = *(const u16x4*)(g3 + i * 4);
            f32x4 f;
#pragma unroll
            for (int k = 0; k < 4; ++k)
                f[k] = (b2f(v0[k]) + b2f(v1[k])) + (b2f(v2[k]) + b2f(v3[k]));
            *(f32x4*)(&encL[i * 4]) = f;
        }
    }
    if (tid < 64) vl[tid] = v_[tid];
    const float bv0 = bv_[0];

    FragU wdh[2], wdl[2], ufh[3][2], ufl[3][2], wch[3][2], wcl[3][2];
    float b1[3];
#pragma unroll
    for (int kf = 0; kf < 2; ++kf)
#pragma unroll
        for (int j = 0; j < 8; ++j) {
            float f = Wd[(kf * 32 + q * 8 + j) * 64 + jw + ln];
            split2(f, wdh[kf].u[j], wdl[kf].u[j]);
        }
#pragma unroll
    for (int g = 0; g < 3; ++g) {
        int col = g * 64 + jw + ln;
#pragma unroll
        for (int kf = 0; kf < 2; ++kf)
#pragma unroll
            for (int j = 0; j < 8; ++j) {
                int k = kf * 32 + q * 8 + j;
                float fu = dec_U[k * 192 + col];
                split2(fu, ufh[g][kf].u[j], ufl[g][kf].u[j]);
                float fc = dec_W[(64 + k) * 192 + col];
                split2(fc, wch[g][kf].u[j], wcl[g][kf].u[j]);
            }
        b1[g] = dec_b[192 + col];
    }
    const float bd_ = bd[jw + ln];

    // ---- step-invariant exp(2e) cache in VGPRs: this thread's (b,s) pair ----
    float Ee[64];
    {
        const int bb2 = t2 >> 5, ss = t2 & 31;
        const u16* ep = &encpT[(size_t)(b0 + bb2) * 2048 + ss];
#pragma unroll
        for (int a = 0; a < 64; ++a) Ee[a] = __expf(b2f(ep[a * 32]));
    }

    // prefetch t=0 x-gates (BOW = 1 for all rows)
    float xg[3][4];
#pragma unroll
    for (int g = 0; g < 3; ++g) {
        float f = xpvd[1 * 192 + g * 64 + jw + ln];
#pragma unroll
        for (int i = 0; i < 4; ++i) xg[g][i] = f;
    }
    __syncthreads();   // enc_lds + vl ready

    // SVB = bias_v + sum_a v[a]   (logit = SVB - 2 * sum_a v[a]/(E+1))
    float SVB = bv0;
#pragma unroll
    for (int a = 0; a < 64; ++a) SVB += vl[a];

    // h0 = encoded[:,0]; zero-pad rows 8..15 of h and ctx tiles
    for (int i = t2; i < 16 * 64; i += 256) {
        int r = i >> 6, c = i & 63;
        if (r < 8) {
            u16 hi, lo; split2(encL[r * 2048 + c], hi, lo);
            hqhL[r * 72 + c] = hi; hqlL[r * 72 + c] = lo;
        } else {
            hqhL[r * 72 + c] = 0; hqlL[r * 72 + c] = 0;
            cxhL[r * 72 + c] = 0; cxlL[r * 72 + c] = 0;
        }
    }
    float hp[4];
#pragma unroll
    for (int i = 0; i < 4; ++i)
        hp[i] = rowok ? encL[(q * 4 + i) * 2048 + jw + ln] : 0.f;
    __syncthreads();

    for (int t = 0; t < 32; ++t) {
        // prefetch next step's x-gates: dec_in[t+1] = tgt[t]
        float xgn[3][4];
        {
            int tn = (t >= 31) ? 30 : t;
#pragma unroll
            for (int i = 0; i < 4; ++i) {
                int rowv = b0 + ((q * 4 + i) & 7);
                int id = tgt_ids[rowv * 32 + tn];
#pragma unroll
                for (int g = 0; g < 3; ++g) xgn[g][i] = xpvd[id * 192 + g * 64 + jw + ln];
            }
        }
        bf16x8 ah0 = load_afrag(&hqhL[ln * 72 + q * 8]);
        bf16x8 ah1 = load_afrag(&hqhL[ln * 72 + 32 + q * 8]);
        bf16x8 al0 = load_afrag(&hqlL[ln * 72 + q * 8]);
        bf16x8 al1 = load_afrag(&hqlL[ln * 72 + 32 + q * 8]);
        // edl = exp(2*(h@Wd + bd))
        {
            f32x4 a = {0.f, 0.f, 0.f, 0.f};
            a = mfma16(al0, wdh[0].v, a);
            a = mfma16(ah0, wdl[0].v, a);
            a = mfma16(ah0, wdh[0].v, a);
            a = mfma16(al1, wdh[1].v, a);
            a = mfma16(ah1, wdl[1].v, a);
            a = mfma16(ah1, wdh[1].v, a);
            if (rowok) {
#pragma unroll
                for (int i = 0; i < 4; ++i)
                    edlL[(q * 4 + i) * 72 + jw + ln] = __expf((a[i] + bd_) * 2.0f);
            }
        }
        __syncthreads();
        // scores + softmax over S: E = E_d * E_e; tanh = 1 - 2/(E+1)
        {
            const int bb2 = t2 >> 5, sidx = t2 & 31;
            const float* dp = &edlL[bb2 * 72];
            float av0 = 0.f, av1 = 0.f, av2 = 0.f, av3 = 0.f;
#pragma unroll
            for (int a4 = 0; a4 < 16; ++a4) {
                f32x4 dv = *(const f32x4*)(dp + a4 * 4);
                av0 += vl[a4 * 4 + 0] * rcp_(__builtin_fmaf(dv[0], Ee[a4 * 4 + 0], 1.0f));
                av1 += vl[a4 * 4 + 1] * rcp_(__builtin_fmaf(dv[1], Ee[a4 * 4 + 1], 1.0f));
                av2 += vl[a4 * 4 + 2] * rcp_(__builtin_fmaf(dv[2], Ee[a4 * 4 + 2], 1.0f));
                av3 += vl[a4 * 4 + 3] * rcp_(__builtin_fmaf(dv[3], Ee[a4 * 4 + 3], 1.0f));
            }
            float logit = SVB - 2.0f * ((av0 + av1) + (av2 + av3));
            float m = logit;
#pragma unroll
            for (int off = 16; off > 0; off >>= 1) m = fmaxf(m, __shfl_xor(m, off, 32));
            float e2 = __expf(logit - m);
            float ssum = e2;
#pragma unroll
            for (int off = 16; off > 0; off >>= 1) ssum += __shfl_xor(ssum, off, 32);
            wlL[bb2 * 36 + sidx] = e2 * rcp_(ssum);
        }
        __syncthreads();
        // ctx = sum_s w[s] * encoded[b,s,:]  — LDS-only, wave-per-row sweep
#pragma unroll
        for (int rr2 = 0; rr2 < 2; ++rr2) {
            const int b = rr2 * 4 + w;
            float c0 = 0.f, c1 = 0.f, c2 = 0.f, c3 = 0.f;
#pragma unroll
            for (int s4 = 0; s4 < 8; ++s4) {
                const int s = s4 * 4 + q;
                const float ww = wlL[b * 36 + s];
                f32x4 ev = *(const f32x4*)(&encL[b * 2048 + s * 64 + ln * 4]);
                c0 += ww * ev[0]; c1 += ww * ev[1];
                c2 += ww * ev[2]; c3 += ww * ev[3];
            }
            c0 += __shfl_xor(c0, 16); c0 += __shfl_xor(c0, 32);
            c1 += __shfl_xor(c1, 16); c1 += __shfl_xor(c1, 32);
            c2 += __shfl_xor(c2, 16); c2 += __shfl_xor(c2, 32);
            c3 += __shfl_xor(c3, 16); c3 += __shfl_xor(c3, 32);
            if (q == 0) {
                u16x4 vh, vo;
                u16 th, tl2;
                split2(c0, th, tl2); vh[0] = th; vo[0] = tl2;
                split2(c1, th, tl2); vh[1] = th; vo[1] = tl2;
                split2(c2, th, tl2); vh[2] = th; vo[2] = tl2;
                split2(c3, th, tl2); vh[3] = th; vo[3] = tl2;
                *(u16x4*)(&cxhL[b * 72 + ln * 4]) = vh;
                *(u16x4*)(&cxlL[b * 72 + ln * 4]) = vo;
            }
        }
        __syncthreads();
        // GRU gates: ax[g] = ctx@Wc (input path), ahh[g] = h@U (recurrent)
        bf16x8 ac0 = load_afrag(&cxhL[ln * 72 + q * 8]);
        bf16x8 ac1 = load_afrag(&cxhL[ln * 72 + 32 + q * 8]);
        bf16x8 al2 = load_afrag(&cxlL[ln * 72 + q * 8]);
        bf16x8 al3 = load_afrag(&cxlL[ln * 72 + 32 + q * 8]);
        f32x4 ax[3], ahh[3];
#pragma unroll
        for (int g = 0; g < 3; ++g) {
            f32x4 a = {0.f, 0.f, 0.f, 0.f};
            a = mfma16(al2, wch[g][0].v, a);
            a = mfma16(ac0, wcl[g][0].v, a);
            a = mfma16(ac0, wch[g][0].v, a);
            a = mfma16(al3, wch[g][1].v, a);
            a = mfma16(ac1, wcl[g][1].v, a);
            a = mfma16(ac1, wch[g][1].v, a);
            ax[g] = a;
            f32x4 h = {0.f, 0.f, 0.f, 0.f};
            h = mfma16(al0, ufh[g][0].v, h);
            h = mfma16(ah0, ufl[g][0].v, h);
            h = mfma16(ah0, ufh[g][0].v, h);
            h = mfma16(al1, ufh[g][1].v, h);
            h = mfma16(ah1, ufl[g][1].v, h);
            h = mfma16(ah1, ufh[g][1].v, h);
            ahh[g] = h;
        }
        float nh[4];
#pragma unroll
        for (int i = 0; i < 4; ++i) {
            int rowg = b0 + q * 4 + i;
            float zz = sigm_(xg[0][i] + ax[0][i] + ahh[0][i] + b1[0]);
            float rr = sigm_(xg[1][i] + ax[1][i] + ahh[1][i] + b1[1]);
            float nn = tanh_(xg[2][i] + ax[2][i] + rr * (ahh[2][i] + b1[2]));
            nh[i] = zz * hp[i] + (1.0f - zz) * nn;  hp[i] = nh[i];
            if (rowok) {
                int gidx = (rowg * 32 + t) * 64 + jw + ln;
                u16 hi, lo; split2(nh[i], hi, lo);
                hid_hi[gidx] = hi; hid_lo[gidx] = lo;
                hqhL[(q * 4 + i) * 72 + jw + ln] = hi;
                hqlL[(q * 4 + i) * 72 + jw + ln] = lo;
            }
        }
        // h-tile writes ordered for step t+1 by the barrier below.
        __syncthreads();
#pragma unroll
        for (int g = 0; g < 3; ++g)
#pragma unroll
            for (int i = 0; i < 4; ++i) xg[g][i] = xgn[g][i];
    }
}

// ---------------------------------------------------------------------------
extern "C" void kernel_launch(void* const* d_in, const int* in_sizes, int n_in,
                              void* d_out, int out_size, void* d_ws, size_t ws_size,
                              hipStream_t stream) {
    const int*   src_ids = (const int*)d_in[0];
    const int*   tgt_ids = (const int*)d_in[1];
    const float* src_emb = (const float*)d_in[2];
    const float* enc_Wf  = (const float*)d_in[3];
    const float* enc_Uf  = (const float*)d_in[4];
    const float* enc_bf  = (const float*)d_in[5];
    const float* enc_Wb  = (const float*)d_in[6];
    const float* enc_Ub  = (const float*)d_in[7];
    const float* enc_bb  = (const float*)d_in[8];
    const float* attn_We = (const float*)d_in[9];
    const float* attn_be = (const float*)d_in[10];
    const float* attn_Wd = (const float*)d_in[11];
    const float* attn_bd = (const float*)d_in[12];
    const float* attn_v  = (const float*)d_in[13];
    const float* attn_bv = (const float*)d_in[14];
    const float* dec_W   = (const float*)d_in[15];
    const float* dec_U   = (const float*)d_in[16];
    const float* dec_b   = (const float*)d_in[17];
    const float* out_W   = (const float*)d_in[18];
    const float* out_b   = (const float*)d_in[19];

    // ws layout (u16 units). fwd [0,16)/[16,32) MiB, bwd [32,48)/[48,64),
    // encpT [64,80), xpv_f/xpv_b/xpvd after 80 MiB. hid reuses fwd planes
    // (dec reads its own rows before overwriting them).
    u16* ws = (u16*)d_ws;
    u16* fwd_hi = ws;
    u16* fwd_lo = ws +  8388608;
    u16* bwd_hi = ws + 16777216;
    u16* bwd_lo = ws + 25165824;
    u16* encpT  = ws + 33554432;
    float* xpv_f = (float*)(ws + 41943040);
    float* xpv_b = (float*)(ws + 42041344);
    float* xpvd  = (float*)(ws + 42139648);
    u16* hid_hi = fwd_hi;
    u16* hid_lo = fwd_lo;

    dim3 blk(256);
    xpv_all<<<12, blk, 0, stream>>>(src_emb, enc_Wf, enc_bf, xpv_f,
                                    enc_Wb, enc_bb, xpv_b,
                                    out_W, dec_W, dec_b, xpvd);
    enc8<<<1024, blk, 0, stream>>>(src_ids, xpv_f, xpv_b, enc_Uf, enc_bf,
                                   enc_Ub, enc_bb, fwd_hi, fwd_lo, bwd_hi, bwd_lo);
    gemm_hl<2, 64, 64><<<2048, blk, 0, stream>>>(
        nullptr, fwd_hi, fwd_lo, bwd_hi, bwd_lo, attn_We, attn_be, nullptr, encpT);
    dec_kernel<<<256, dim3(512), 0, stream>>>(tgt_ids, xpvd, fwd_hi, fwd_lo,
                                              bwd_hi, bwd_lo, encpT,
                                              dec_U, dec_W, dec_b,
                                              attn_Wd, attn_bd, attn_v, attn_bv,
                                              hid_hi, hid_lo);
    gemm_hl<3, 64, 256><<<2048, blk, 0, stream>>>(
        nullptr, hid_hi, hid_lo, nullptr, nullptr, out_W, out_b, (float*)d_out, nullptr);
}

// Round 7
// 693.019 us; speedup vs baseline: 1.4213x; 1.4181x over previous
//
#include <hip/hip_runtime.h>
#include <hip/hip_bf16.h>

// ---------- types / helpers ----------
typedef unsigned short u16;
typedef __bf16  bf16x8 __attribute__((ext_vector_type(8)));
typedef float   f32x4  __attribute__((ext_vector_type(4)));
typedef unsigned int   u32x4 __attribute__((ext_vector_type(4)));
typedef unsigned short u16x4 __attribute__((ext_vector_type(4)));

union FragU { bf16x8 v; u16 u[8]; u32x4 q; };

__device__ __forceinline__ float b2f(u16 u) {
    unsigned int x = ((unsigned int)u) << 16;
    return __builtin_bit_cast(float, x);
}
__device__ __forceinline__ u16 f2b(float f) {
    unsigned int x = __builtin_bit_cast(unsigned int, f);
    unsigned int r = (x + 0x7fffu + ((x >> 16) & 1u)) >> 16;
    return (u16)r;
}
__device__ __forceinline__ float rcp_(float x) { return __builtin_amdgcn_rcpf(x); }
__device__ __forceinline__ float sigm_(float x) { return rcp_(1.0f + __expf(-x)); }
__device__ __forceinline__ float tanh_(float x) {
    float e = __expf(2.0f * x);
    return 1.0f - 2.0f * rcp_(e + 1.0f);
}
__device__ __forceinline__ bf16x8 load_afrag(const u16* s) {
    FragU f; f.q = *(const u32x4*)s; return f.v;
}
__device__ __forceinline__ f32x4 mfma16(bf16x8 a, bf16x8 b, f32x4 c) {
    return __builtin_amdgcn_mfma_f32_16x16x32_bf16(a, b, c, 0, 0, 0);
}
// split helper: hi bf16 + residual lo bf16
__device__ __forceinline__ void split2(float f, u16& hi, u16& lo) {
    hi = f2b(f); lo = f2b(f - b2f(hi));
}

// ---------------------------------------------------------------------------
// Split-bf16 GEMM body (effective-fp32): out = A @ W + bias (3 MFMAs/product)
// MODE 0: vocab-enc  A[256,128] = src_emb,      out xpv fp32 [256,192]
// MODE 1: vocab-dec  A[256,64]  = out_W^T * 8,  out xpv fp32 [256,192]
// MODE 2: enc_proj   A = fwd+bwd (4 bf16 planes), K=64,N=64,
//         out bf16 encpT[b][s][a] = (acc+be)*2   (row-contiguous in a!)
// MODE 3: logits     A = hid hi/lo planes, K=64,N=256, out fp32 d_out
// 256 thr, 64 rows; wave w covers cols [w*N/4,(w+1)*N/4)
// ---------------------------------------------------------------------------
template<int MODE, int K, int N>
__device__ __forceinline__ void gemm_body(
    const float* __restrict__ srcf, const u16* __restrict__ sh,
    const u16* __restrict__ sl, const u16* __restrict__ sh2,
    const u16* __restrict__ sl2, const float* __restrict__ W,
    const float* __restrict__ bias, float* __restrict__ outf,
    u16* __restrict__ outh, int rbase)
{
    constexpr int KP = K + 8;
    constexpr int LK = (K == 128) ? 7 : 6;
    __shared__ __attribute__((aligned(16))) u16 Ash[64 * KP];
    __shared__ __attribute__((aligned(16))) u16 Asl[64 * KP];

    const int tid  = threadIdx.x;
    const int lane = tid & 63, w = tid >> 6;
    const int q = lane >> 4, ln = lane & 15;

    // ---- stage A rows into LDS hi/lo ----
    for (int i = tid; i < 64 * K; i += 256) {
        int r = i >> LK, c = i & (K - 1);
        int rg = rbase + r;
        float f;
        if constexpr (MODE == 0)      f = srcf[rg * K + c];
        else if constexpr (MODE == 1) f = srcf[c * 256 + rg] * 8.0f;
        else if constexpr (MODE == 2)
            f = b2f(sh[rg * 64 + c]) + b2f(sl[rg * 64 + c])
              + b2f(sh2[rg * 64 + c]) + b2f(sl2[rg * 64 + c]);
        else                          f = b2f(sh[rg * 64 + c]) + b2f(sl[rg * 64 + c]);
        u16 hi, lo; split2(f, hi, lo);
        Ash[r * KP + c] = hi; Asl[r * KP + c] = lo;
    }

    // ---- B fragments hi/lo in registers ----
    constexpr int NT  = N / 64;
    constexpr int NKF = K / 32;
    FragU bfh[NT][NKF], bfl[NT][NKF];
    float bv[NT];
    const int cw = w * (N >> 2);
#pragma unroll
    for (int tl = 0; tl < NT; ++tl) {
        int col = cw + tl * 16 + ln;
#pragma unroll
        for (int kf = 0; kf < NKF; ++kf)
#pragma unroll
            for (int j = 0; j < 8; ++j) {
                float f = W[(kf * 32 + q * 8 + j) * N + col];
                split2(f, bfh[tl][kf].u[j], bfl[tl][kf].u[j]);
            }
        bv[tl] = bias[col];
    }
    __syncthreads();

#pragma unroll
    for (int r = 0; r < 4; ++r) {
        bf16x8 afh[NKF], afl[NKF];
#pragma unroll
        for (int kf = 0; kf < NKF; ++kf) {
            afh[kf] = load_afrag(&Ash[(r * 16 + ln) * KP + kf * 32 + q * 8]);
            afl[kf] = load_afrag(&Asl[(r * 16 + ln) * KP + kf * 32 + q * 8]);
        }
#pragma unroll
        for (int tl = 0; tl < NT; ++tl) {
            f32x4 acc = {0.f, 0.f, 0.f, 0.f};
#pragma unroll
            for (int kf = 0; kf < NKF; ++kf) {
                acc = mfma16(afl[kf], bfh[tl][kf].v, acc);
                acc = mfma16(afh[kf], bfl[tl][kf].v, acc);
                acc = mfma16(afh[kf], bfh[tl][kf].v, acc);
            }
            const int col = cw + tl * 16 + ln;
#pragma unroll
            for (int i = 0; i < 4; ++i) {
                int rowg = rbase + r * 16 + q * 4 + i;
                float val = acc[i] + bv[tl];
                if constexpr (MODE == 2) {
                    // encpT layout [b][s][a]: rowg = b*32+s, col = a
                    outh[rowg * 64 + col] = f2b(val * 2.0f);
                } else if constexpr (MODE == 3) {
                    outf[rowg * N + col] = val;
                } else {
                    outf[rowg * 192 + col] = val;
                }
            }
        }
    }
}

template<int MODE, int K, int N>
__global__ __launch_bounds__(256, (MODE >= 2) ? 2 : 1) void gemm_hl(
    const float* __restrict__ srcf, const u16* __restrict__ sh,
    const u16* __restrict__ sl, const u16* __restrict__ sh2,
    const u16* __restrict__ sl2, const float* __restrict__ W,
    const float* __restrict__ bias, float* __restrict__ outf,
    u16* __restrict__ outh)
{
    gemm_body<MODE, K, N>(srcf, sh, sl, sh2, sl2, W, bias, outf, outh,
                          (int)blockIdx.x * 64);
}

// All three tiny vocab-table GEMMs in ONE launch (12 blocks): blocks 0-3
// xpv_f, 4-7 xpv_b, 8-11 xpvd. Removes 2 serial dispatch gaps.
__global__ __launch_bounds__(256, 1) void xpv_all(
    const float* __restrict__ src_emb,
    const float* __restrict__ Wf, const float* __restrict__ bf, float* __restrict__ xf,
    const float* __restrict__ Wb, const float* __restrict__ bb, float* __restrict__ xb,
    const float* __restrict__ outW, const float* __restrict__ dW,
    const float* __restrict__ db, float* __restrict__ xd)
{
    const int b = blockIdx.x;
    if (b < 4)
        gemm_body<0, 128, 192>(src_emb, nullptr, nullptr, nullptr, nullptr,
                               Wf, bf, xf, nullptr, b * 64);
    else if (b < 8)
        gemm_body<0, 128, 192>(src_emb, nullptr, nullptr, nullptr, nullptr,
                               Wb, bb, xb, nullptr, (b - 4) * 64);
    else
        gemm_body<1, 64, 192>(outW, nullptr, nullptr, nullptr, nullptr,
                              dW, db, xd, nullptr, (b - 8) * 64);
}

// ---------------------------------------------------------------------------
// Fused bidirectional encoder GRU (split-bf16), 8 rows/block, 1024 blocks
// (blocks [0,512) = forward, [512,1024) = backward). Backward writes its own
// planes (bh/bl); fwd+bwd sum is folded into the MODE-2 gemm / dec staging.
// MFMA batch rows 8..15 are zero padding; writes guarded to q<2.
// ---------------------------------------------------------------------------
__global__ __launch_bounds__(256, 2) void enc8(
    const int* __restrict__ src_ids, const float* __restrict__ xf,
    const float* __restrict__ xb,
    const float* __restrict__ Uf_, const float* __restrict__ bf_,
    const float* __restrict__ Ub_, const float* __restrict__ bb_,
    u16* __restrict__ fh, u16* __restrict__ fl,
    u16* __restrict__ bh, u16* __restrict__ bl)
{
    __shared__ __attribute__((aligned(16))) u16 hsh[16 * 72];
    __shared__ __attribute__((aligned(16))) u16 hsl[16 * 72];
    const int tid  = threadIdx.x;
    const int lane = tid & 63, w = tid >> 6;
    const int q = lane >> 4, ln = lane & 15;
    const int dir = (int)(blockIdx.x >> 9);
    const int b0  = (int)(blockIdx.x & 511) * 8;
    const float* xpv = dir ? xb  : xf;
    const float* U   = dir ? Ub_ : Uf_;
    const float* b_  = dir ? bb_ : bf_;
    u16* oh = dir ? bh : fh;
    u16* ol = dir ? bl : fl;
    const int jw = w * 16;
    const bool rowok = (q < 2);

    for (int i = tid; i < 16 * 64; i += 256) {
        int r = i >> 6, c = i & 63;
        hsh[r * 72 + c] = 0; hsl[r * 72 + c] = 0;
    }
    FragU ufh[3][2], ufl[3][2];
    float b1[3];
#pragma unroll
    for (int g = 0; g < 3; ++g) {
        int col = g * 64 + jw + ln;
#pragma unroll
        for (int kf = 0; kf < 2; ++kf)
#pragma unroll
            for (int j = 0; j < 8; ++j) {
                float f = U[(kf * 32 + q * 8 + j) * 192 + col];
                split2(f, ufh[g][kf].u[j], ufl[g][kf].u[j]);
            }
        b1[g] = b_[192 + col];
    }
    float hp[4] = {0, 0, 0, 0};

    // prefetch x-gates for first step (rows clamped in-bounds for pad lanes)
    float xg[3][4];
    {
        const int s0 = dir ? 31 : 0;
#pragma unroll
        for (int i = 0; i < 4; ++i) {
            int rowv = b0 + ((q * 4 + i) & 7);
            int id = src_ids[rowv * 32 + s0];
#pragma unroll
            for (int g = 0; g < 3; ++g) xg[g][i] = xpv[id * 192 + g * 64 + jw + ln];
        }
    }
    __syncthreads();

    for (int step = 0; step < 32; ++step) {
        const int s = dir ? (31 - step) : step;
        // prefetch next step's x-gates
        float xgn[3][4];
        {
            int sn = dir ? (step >= 31 ? 0 : 30 - step) : (step >= 31 ? 31 : step + 1);
#pragma unroll
            for (int i = 0; i < 4; ++i) {
                int rowv = b0 + ((q * 4 + i) & 7);
                int id = src_ids[rowv * 32 + sn];
#pragma unroll
                for (int g = 0; g < 3; ++g) xgn[g][i] = xpv[id * 192 + g * 64 + jw + ln];
            }
        }
        bf16x8 a0h = load_afrag(&hsh[ln * 72 + q * 8]);
        bf16x8 a1h = load_afrag(&hsh[ln * 72 + 32 + q * 8]);
        bf16x8 a0l = load_afrag(&hsl[ln * 72 + q * 8]);
        bf16x8 a1l = load_afrag(&hsl[ln * 72 + 32 + q * 8]);
        f32x4 acc[3];
#pragma unroll
        for (int g = 0; g < 3; ++g) {
            f32x4 a = {0.f, 0.f, 0.f, 0.f};
            a = mfma16(a0l, ufh[g][0].v, a);
            a = mfma16(a0h, ufl[g][0].v, a);
            a = mfma16(a0h, ufh[g][0].v, a);
            a = mfma16(a1l, ufh[g][1].v, a);
            a = mfma16(a1h, ufl[g][1].v, a);
            a = mfma16(a1h, ufh[g][1].v, a);
            acc[g] = a;
        }
        float nh[4];
#pragma unroll
        for (int i = 0; i < 4; ++i) {
            const int rowg = b0 + q * 4 + i;
            float zz = sigm_(xg[0][i] + acc[0][i] + b1[0]);
            float rr = sigm_(xg[1][i] + acc[1][i] + b1[1]);
            float nn = tanh_(xg[2][i] + rr * (acc[2][i] + b1[2]));
            nh[i] = zz * hp[i] + (1.0f - zz) * nn;  hp[i] = nh[i];
            if (rowok) {
                const int gidx = (rowg * 32 + s) * 64 + jw + ln;
                u16 hi, lo; split2(nh[i], hi, lo);
                oh[gidx] = hi; ol[gidx] = lo;
            }
        }
        __syncthreads();
        if (rowok) {
#pragma unroll
            for (int i = 0; i < 4; ++i) {
                u16 hi, lo; split2(nh[i], hi, lo);
                hsh[(q * 4 + i) * 72 + jw + ln] = hi;
                hsl[(q * 4 + i) * 72 + jw + ln] = lo;
            }
        }
        __syncthreads();
#pragma unroll
        for (int g = 0; g < 3; ++g)
#pragma unroll
            for (int i = 0; i < 4; ++i) xg[g][i] = xgn[g][i];
    }
}

// ---------------------------------------------------------------------------
// Decoder: Bahdanau attention + GRU, split-bf16; 8 rows/block, 512 blocks.
// Register-diet version: the 64-VGPR step-invariant exp cache (Ee) is GONE;
// the scores loop instead reads its encpT row ([b][s][a] layout, contiguous,
// 8x b128 loads/step, L1/L2-resident 32 KB slice) and computes exp inline.
// Arch demand drops ~176 -> ~115, so launch_bounds(256,2) (128-reg cap) no
// longer spills (R2's spill was demand 176 > cap 128) AND caps the unified
// reg total so the HW can co-schedule 2 blocks/CU -> 2 waves/SIMD.
// LDS 78.8 KiB x 2 = 157.7 <= 160 KiB (512 B granule, measured R3).
// ---------------------------------------------------------------------------
__global__ __launch_bounds__(256, 2) void dec_kernel(
    const int* __restrict__ tgt_ids, const float* __restrict__ xpvd,
    const u16* __restrict__ fh, const u16* __restrict__ fl,
    const u16* __restrict__ bh, const u16* __restrict__ bl,
    const u16* __restrict__ encpT,
    const float* __restrict__ dec_U, const float* __restrict__ dec_W,
    const float* __restrict__ dec_b,
    const float* __restrict__ Wd, const float* __restrict__ bd,
    const float* __restrict__ v_, const float* __restrict__ bv_,
    u16* __restrict__ hid_hi, u16* __restrict__ hid_lo)
{
    __shared__ __attribute__((aligned(16))) float enc_lds[8 * 2048]; // 64 KiB
    __shared__ __attribute__((aligned(16))) u16 hqh[16 * 72];
    __shared__ __attribute__((aligned(16))) u16 hql[16 * 72];
    __shared__ __attribute__((aligned(16))) u16 cxh[16 * 72];
    __shared__ __attribute__((aligned(16))) u16 cxl[16 * 72];
    __shared__ __attribute__((aligned(16))) float dpl[8 * 72];       // 2*(dproj+bd)
    __shared__ float wl[8 * 36];
    __shared__ float vl[64];
    const int tid  = threadIdx.x;
    const int lane = tid & 63, w = tid >> 6;
    const int q = lane >> 4, ln = lane & 15;
    const int b0 = blockIdx.x * 8;
    const int jw = w * 16;
    const bool rowok = (q < 2);

    // ---- stage encoded = fwd_hi+fwd_lo+bwd_hi+bwd_lo (fp32) into LDS ----
    {
        const u16* g0 = fh + (size_t)b0 * 2048;
        const u16* g1 = fl + (size_t)b0 * 2048;
        const u16* g2 = bh + (size_t)b0 * 2048;
        const u16* g3 = bl + (size_t)b0 * 2048;
        for (int i = tid; i < 8 * 2048 / 4; i += 256) {
            u16x4 v0 = *(const u16x4*)(g0 + i * 4);
            u16x4 v1 = *(const u16x4*)(g1 + i * 4);
            u16x4 v2 = *(const u16x4*)(g2 + i * 4);
            u16x4 v3 = *(const u16x4*)(g3 + i * 4);
            f32x4 f;
#pragma unroll
            for (int k = 0; k < 4; ++k)
                f[k] = (b2f(v0[k]) + b2f(v1[k])) + (b2f(v2[k]) + b2f(v3[k]));
            *(f32x4*)(&enc_lds[i * 4]) = f;
        }
    }
    if (tid < 64) vl[tid] = v_[tid];
    const float bv0 = bv_[0];

    FragU wdh[2], wdl[2], ufh[3][2], ufl[3][2], wch[3][2], wcl[3][2];
    float b1[3];
#pragma unroll
    for (int kf = 0; kf < 2; ++kf)
#pragma unroll
        for (int j = 0; j < 8; ++j) {
            float f = Wd[(kf * 32 + q * 8 + j) * 64 + jw + ln];
            split2(f, wdh[kf].u[j], wdl[kf].u[j]);
        }
#pragma unroll
    for (int g = 0; g < 3; ++g) {
        int col = g * 64 + jw + ln;
#pragma unroll
        for (int kf = 0; kf < 2; ++kf)
#pragma unroll
            for (int j = 0; j < 8; ++j) {
                int k = kf * 32 + q * 8 + j;
                float fu = dec_U[k * 192 + col];
                split2(fu, ufh[g][kf].u[j], ufl[g][kf].u[j]);
                float fc = dec_W[(64 + k) * 192 + col];
                split2(fc, wch[g][kf].u[j], wcl[g][kf].u[j]);
            }
        b1[g] = dec_b[192 + col];
    }
    const float bd_ = bd[jw + ln];

    // step-invariant pointer to this thread's e-row (contiguous 64 bf16)
    const int bb2 = tid >> 5, ss = tid & 31;
    const u16* ep = &encpT[((size_t)(b0 + bb2) * 32 + ss) * 64];

    // prefetch t=0 x-gates (BOW = 1 for all rows)
    float xg[3][4];
#pragma unroll
    for (int g = 0; g < 3; ++g) {
        float f = xpvd[1 * 192 + g * 64 + jw + ln];
#pragma unroll
        for (int i = 0; i < 4; ++i) xg[g][i] = f;
    }
    __syncthreads();   // enc_lds + vl ready

    // SVB = bias_v + sum_a v[a]   (logit = SVB - 2 * sum_a v[a]/(E+1))
    float SVB = bv0;
#pragma unroll
    for (int a = 0; a < 64; ++a) SVB += vl[a];

    // h0 = encoded[:,0]; zero-pad rows 8..15 of h and ctx tiles
    for (int i = tid; i < 16 * 64; i += 256) {
        int r = i >> 6, c = i & 63;
        if (r < 8) {
            u16 hi, lo; split2(enc_lds[r * 2048 + c], hi, lo);
            hqh[r * 72 + c] = hi; hql[r * 72 + c] = lo;
        } else {
            hqh[r * 72 + c] = 0; hql[r * 72 + c] = 0;
            cxh[r * 72 + c] = 0; cxl[r * 72 + c] = 0;
        }
    }
    float hp[4];
#pragma unroll
    for (int i = 0; i < 4; ++i)
        hp[i] = rowok ? enc_lds[(q * 4 + i) * 2048 + jw + ln] : 0.f;
    __syncthreads();

    for (int t = 0; t < 32; ++t) {
        // prefetch next step's x-gates: dec_in[t+1] = tgt[t]
        float xgn[3][4];
        {
            int tn = (t >= 31) ? 30 : t;
#pragma unroll
            for (int i = 0; i < 4; ++i) {
                int rowv = b0 + ((q * 4 + i) & 7);
                int id = tgt_ids[rowv * 32 + tn];
#pragma unroll
                for (int g = 0; g < 3; ++g) xgn[g][i] = xpvd[id * 192 + g * 64 + jw + ln];
            }
        }
        bf16x8 ah0 = load_afrag(&hqh[ln * 72 + q * 8]);
        bf16x8 ah1 = load_afrag(&hqh[ln * 72 + 32 + q * 8]);
        bf16x8 al0 = load_afrag(&hql[ln * 72 + q * 8]);
        bf16x8 al1 = load_afrag(&hql[ln * 72 + 32 + q * 8]);
        // dpl = 2*(h@Wd + bd)
        {
            f32x4 a = {0.f, 0.f, 0.f, 0.f};
            a = mfma16(al0, wdh[0].v, a);
            a = mfma16(ah0, wdl[0].v, a);
            a = mfma16(ah0, wdh[0].v, a);
            a = mfma16(al1, wdh[1].v, a);
            a = mfma16(ah1, wdl[1].v, a);
            a = mfma16(ah1, wdh[1].v, a);
            if (rowok) {
#pragma unroll
                for (int i = 0; i < 4; ++i)
                    dpl[(q * 4 + i) * 72 + jw + ln] = (a[i] + bd_) * 2.0f;
            }
        }
        __syncthreads();
        // scores + softmax over S: tanh(d+e) = 1 - 2/(exp(2d+2e)+1)
        // e-row read from global (L1/L2-hit, 8x b128), exp inline.
        {
            const float* dp = &dpl[bb2 * 72];
            float av0 = 0.f, av1 = 0.f, av2 = 0.f, av3 = 0.f;
#pragma unroll
            for (int a8 = 0; a8 < 8; ++a8) {
                FragU ev; ev.q = *(const u32x4*)(ep + a8 * 8);
                f32x4 d0 = *(const f32x4*)(dp + a8 * 8);
                f32x4 d1 = *(const f32x4*)(dp + a8 * 8 + 4);
#pragma unroll
                for (int j = 0; j < 8; ++j) {
                    const int a = a8 * 8 + j;
                    float u = (j < 4 ? d0[j & 3] : d1[j & 3]) + b2f(ev.u[j]);
                    float E = __expf(u);
                    float rc = vl[a] * rcp_(E + 1.0f);
                    if ((j & 3) == 0)      av0 += rc;
                    else if ((j & 3) == 1) av1 += rc;
                    else if ((j & 3) == 2) av2 += rc;
                    else                   av3 += rc;
                }
            }
            float logit = SVB - 2.0f * ((av0 + av1) + (av2 + av3));
            float m = logit;
#pragma unroll
            for (int off = 16; off > 0; off >>= 1) m = fmaxf(m, __shfl_xor(m, off, 32));
            float e2 = __expf(logit - m);
            float ssum = e2;
#pragma unroll
            for (int off = 16; off > 0; off >>= 1) ssum += __shfl_xor(ssum, off, 32);
            wl[bb2 * 36 + ss] = e2 * rcp_(ssum);
        }
        __syncthreads();
        // ctx = sum_s w[s] * encoded[b,s,:]  — LDS-only, wave-per-row sweep
#pragma unroll
        for (int rr2 = 0; rr2 < 2; ++rr2) {
            const int b = rr2 * 4 + w;
            float c0 = 0.f, c1 = 0.f, c2 = 0.f, c3 = 0.f;
#pragma unroll
            for (int s4 = 0; s4 < 8; ++s4) {
                const int s = s4 * 4 + q;
                const float ww = wl[b * 36 + s];
                f32x4 ev = *(const f32x4*)(&enc_lds[b * 2048 + s * 64 + ln * 4]);
                c0 += ww * ev[0]; c1 += ww * ev[1];
                c2 += ww * ev[2]; c3 += ww * ev[3];
            }
            c0 += __shfl_xor(c0, 16); c0 += __shfl_xor(c0, 32);
            c1 += __shfl_xor(c1, 16); c1 += __shfl_xor(c1, 32);
            c2 += __shfl_xor(c2, 16); c2 += __shfl_xor(c2, 32);
            c3 += __shfl_xor(c3, 16); c3 += __shfl_xor(c3, 32);
            if (q == 0) {
                u16x4 vh, vo;
                u16 th, tl2;
                split2(c0, th, tl2); vh[0] = th; vo[0] = tl2;
                split2(c1, th, tl2); vh[1] = th; vo[1] = tl2;
                split2(c2, th, tl2); vh[2] = th; vo[2] = tl2;
                split2(c3, th, tl2); vh[3] = th; vo[3] = tl2;
                *(u16x4*)(&cxh[b * 72 + ln * 4]) = vh;
                *(u16x4*)(&cxl[b * 72 + ln * 4]) = vo;
            }
        }
        __syncthreads();
        // GRU gates: ax[g] = ctx@Wc (input path), ahh[g] = h@U (recurrent)
        bf16x8 ac0 = load_afrag(&cxh[ln * 72 + q * 8]);
        bf16x8 ac1 = load_afrag(&cxh[ln * 72 + 32 + q * 8]);
        bf16x8 al2 = load_afrag(&cxl[ln * 72 + q * 8]);
        bf16x8 al3 = load_afrag(&cxl[ln * 72 + 32 + q * 8]);
        f32x4 ax[3], ahh[3];
#pragma unroll
        for (int g = 0; g < 3; ++g) {
            f32x4 a = {0.f, 0.f, 0.f, 0.f};
            a = mfma16(al2, wch[g][0].v, a);
            a = mfma16(ac0, wcl[g][0].v, a);
            a = mfma16(ac0, wch[g][0].v, a);
            a = mfma16(al3, wch[g][1].v, a);
            a = mfma16(ac1, wcl[g][1].v, a);
            a = mfma16(ac1, wch[g][1].v, a);
            ax[g] = a;
            f32x4 h = {0.f, 0.f, 0.f, 0.f};
            h = mfma16(al0, ufh[g][0].v, h);
            h = mfma16(ah0, ufl[g][0].v, h);
            h = mfma16(ah0, ufh[g][0].v, h);
            h = mfma16(al1, ufh[g][1].v, h);
            h = mfma16(ah1, ufl[g][1].v, h);
            h = mfma16(ah1, ufh[g][1].v, h);
            ahh[g] = h;
        }
        float nh[4];
#pragma unroll
        for (int i = 0; i < 4; ++i) {
            int rowg = b0 + q * 4 + i;
            float zz = sigm_(xg[0][i] + ax[0][i] + ahh[0][i] + b1[0]);
            float rr = sigm_(xg[1][i] + ax[1][i] + ahh[1][i] + b1[1]);
            float nn = tanh_(xg[2][i] + ax[2][i] + rr * (ahh[2][i] + b1[2]));
            nh[i] = zz * hp[i] + (1.0f - zz) * nn;  hp[i] = nh[i];
            if (rowok) {
                int gidx = (rowg * 32 + t) * 64 + jw + ln;
                u16 hi, lo; split2(nh[i], hi, lo);
                hid_hi[gidx] = hi; hid_lo[gidx] = lo;
                hqh[(q * 4 + i) * 72 + jw + ln] = hi;
                hql[(q * 4 + i) * 72 + jw + ln] = lo;
            }
        }
        // h-tile writes ordered for step t+1 by the barrier below.
        __syncthreads();
#pragma unroll
        for (int g = 0; g < 3; ++g)
#pragma unroll
            for (int i = 0; i < 4; ++i) xg[g][i] = xgn[g][i];
    }
}

// ---------------------------------------------------------------------------
extern "C" void kernel_launch(void* const* d_in, const int* in_sizes, int n_in,
                              void* d_out, int out_size, void* d_ws, size_t ws_size,
                              hipStream_t stream) {
    const int*   src_ids = (const int*)d_in[0];
    const int*   tgt_ids = (const int*)d_in[1];
    const float* src_emb = (const float*)d_in[2];
    const float* enc_Wf  = (const float*)d_in[3];
    const float* enc_Uf  = (const float*)d_in[4];
    const float* enc_bf  = (const float*)d_in[5];
    const float* enc_Wb  = (const float*)d_in[6];
    const float* enc_Ub  = (const float*)d_in[7];
    const float* enc_bb  = (const float*)d_in[8];
    const float* attn_We = (const float*)d_in[9];
    const float* attn_be = (const float*)d_in[10];
    const float* attn_Wd = (const float*)d_in[11];
    const float* attn_bd = (const float*)d_in[12];
    const float* attn_v  = (const float*)d_in[13];
    const float* attn_bv = (const float*)d_in[14];
    const float* dec_W   = (const float*)d_in[15];
    const float* dec_U   = (const float*)d_in[16];
    const float* dec_b   = (const float*)d_in[17];
    const float* out_W   = (const float*)d_in[18];
    const float* out_b   = (const float*)d_in[19];

    // ws layout (u16 units). fwd [0,16)/[16,32) MiB, bwd [32,48)/[48,64),
    // encpT [64,80), xpv_f/xpv_b/xpvd after 80 MiB. hid reuses fwd planes
    // (dec reads its own rows before overwriting them).
    u16* ws = (u16*)d_ws;
    u16* fwd_hi = ws;
    u16* fwd_lo = ws +  8388608;
    u16* bwd_hi = ws + 16777216;
    u16* bwd_lo = ws + 25165824;
    u16* encpT  = ws + 33554432;
    float* xpv_f = (float*)(ws + 41943040);
    float* xpv_b = (float*)(ws + 42041344);
    float* xpvd  = (float*)(ws + 42139648);
    u16* hid_hi = fwd_hi;
    u16* hid_lo = fwd_lo;

    dim3 blk(256);
    xpv_all<<<12, blk, 0, stream>>>(src_emb, enc_Wf, enc_bf, xpv_f,
                                    enc_Wb, enc_bb, xpv_b,
                                    out_W, dec_W, dec_b, xpvd);
    enc8<<<1024, blk, 0, stream>>>(src_ids, xpv_f, xpv_b, enc_Uf, enc_bf,
                                   enc_Ub, enc_bb, fwd_hi, fwd_lo, bwd_hi, bwd_lo);
    gemm_hl<2, 64, 64><<<2048, blk, 0, stream>>>(
        nullptr, fwd_hi, fwd_lo, bwd_hi, bwd_lo, attn_We, attn_be, nullptr, encpT);
    dec_kernel<<<512, blk, 0, stream>>>(tgt_ids, xpvd, fwd_hi, fwd_lo,
                                        bwd_hi, bwd_lo, encpT,
                                        dec_U, dec_W, dec_b,
                                        attn_Wd, attn_bd, attn_v, attn_bv,
                                        hid_hi, hid_lo);
    gemm_hl<3, 64, 256><<<2048, blk, 0, stream>>>(
        nullptr, hid_hi, hid_lo, nullptr, nullptr, out_W, out_b, (float*)d_out, nullptr);
}

// Round 8
// 604.266 us; speedup vs baseline: 1.6301x; 1.1469x over previous
//
#include <hip/hip_runtime.h>
#include <hip/hip_bf16.h>

// ---------- types / helpers ----------
typedef unsigned short u16;
typedef __bf16  bf16x8 __attribute__((ext_vector_type(8)));
typedef float   f32x4  __attribute__((ext_vector_type(4)));
typedef unsigned int   u32x4 __attribute__((ext_vector_type(4)));
typedef unsigned short u16x4 __attribute__((ext_vector_type(4)));

union FragU { bf16x8 v; u16 u[8]; u32x4 q; };

__device__ __forceinline__ float b2f(u16 u) {
    unsigned int x = ((unsigned int)u) << 16;
    return __builtin_bit_cast(float, x);
}
__device__ __forceinline__ u16 f2b(float f) {
    unsigned int x = __builtin_bit_cast(unsigned int, f);
    unsigned int r = (x + 0x7fffu + ((x >> 16) & 1u)) >> 16;
    return (u16)r;
}
__device__ __forceinline__ float rcp_(float x) { return __builtin_amdgcn_rcpf(x); }
__device__ __forceinline__ float sigm_(float x) { return rcp_(1.0f + __expf(-x)); }
__device__ __forceinline__ float tanh_(float x) {
    float e = __expf(2.0f * x);
    return 1.0f - 2.0f * rcp_(e + 1.0f);
}
__device__ __forceinline__ bf16x8 load_afrag(const u16* s) {
    FragU f; f.q = *(const u32x4*)s; return f.v;
}
__device__ __forceinline__ f32x4 mfma16(bf16x8 a, bf16x8 b, f32x4 c) {
    return __builtin_amdgcn_mfma_f32_16x16x32_bf16(a, b, c, 0, 0, 0);
}
// split helper: hi bf16 + residual lo bf16
__device__ __forceinline__ void split2(float f, u16& hi, u16& lo) {
    hi = f2b(f); lo = f2b(f - b2f(hi));
}

// ---------------------------------------------------------------------------
// Split-bf16 GEMM body (effective-fp32): out = A @ W + bias (3 MFMAs/product)
// MODE 0: vocab-enc  A[256,128] = src_emb,      out xpv fp32 [256,192]
// MODE 1: vocab-dec  A[256,64]  = out_W^T * 8,  out xpv fp32 [256,192]
// MODE 2: enc_proj   A = fwd+bwd (4 bf16 planes), K=64,N=64,
//         out bf16 encpT[b][s][a] = (acc+be)*2   (row-contiguous in a)
// MODE 3: logits     A = hid hi/lo planes, K=64,N=256, out fp32 d_out
// 256 thr, 64 rows; wave w covers cols [w*N/4,(w+1)*N/4)
// ---------------------------------------------------------------------------
template<int MODE, int K, int N>
__device__ __forceinline__ void gemm_body(
    const float* __restrict__ srcf, const u16* __restrict__ sh,
    const u16* __restrict__ sl, const u16* __restrict__ sh2,
    const u16* __restrict__ sl2, const float* __restrict__ W,
    const float* __restrict__ bias, float* __restrict__ outf,
    u16* __restrict__ outh, int rbase)
{
    constexpr int KP = K + 8;
    constexpr int LK = (K == 128) ? 7 : 6;
    __shared__ __attribute__((aligned(16))) u16 Ash[64 * KP];
    __shared__ __attribute__((aligned(16))) u16 Asl[64 * KP];

    const int tid  = threadIdx.x;
    const int lane = tid & 63, w = tid >> 6;
    const int q = lane >> 4, ln = lane & 15;

    // ---- stage A rows into LDS hi/lo ----
    for (int i = tid; i < 64 * K; i += 256) {
        int r = i >> LK, c = i & (K - 1);
        int rg = rbase + r;
        float f;
        if constexpr (MODE == 0)      f = srcf[rg * K + c];
        else if constexpr (MODE == 1) f = srcf[c * 256 + rg] * 8.0f;
        else if constexpr (MODE == 2)
            f = b2f(sh[rg * 64 + c]) + b2f(sl[rg * 64 + c])
              + b2f(sh2[rg * 64 + c]) + b2f(sl2[rg * 64 + c]);
        else                          f = b2f(sh[rg * 64 + c]) + b2f(sl[rg * 64 + c]);
        u16 hi, lo; split2(f, hi, lo);
        Ash[r * KP + c] = hi; Asl[r * KP + c] = lo;
    }

    // ---- B fragments hi/lo in registers ----
    constexpr int NT  = N / 64;
    constexpr int NKF = K / 32;
    FragU bfh[NT][NKF], bfl[NT][NKF];
    float bv[NT];
    const int cw = w * (N >> 2);
#pragma unroll
    for (int tl = 0; tl < NT; ++tl) {
        int col = cw + tl * 16 + ln;
#pragma unroll
        for (int kf = 0; kf < NKF; ++kf)
#pragma unroll
            for (int j = 0; j < 8; ++j) {
                float f = W[(kf * 32 + q * 8 + j) * N + col];
                split2(f, bfh[tl][kf].u[j], bfl[tl][kf].u[j]);
            }
        bv[tl] = bias[col];
    }
    __syncthreads();

#pragma unroll
    for (int r = 0; r < 4; ++r) {
        bf16x8 afh[NKF], afl[NKF];
#pragma unroll
        for (int kf = 0; kf < NKF; ++kf) {
            afh[kf] = load_afrag(&Ash[(r * 16 + ln) * KP + kf * 32 + q * 8]);
            afl[kf] = load_afrag(&Asl[(r * 16 + ln) * KP + kf * 32 + q * 8]);
        }
#pragma unroll
        for (int tl = 0; tl < NT; ++tl) {
            f32x4 acc = {0.f, 0.f, 0.f, 0.f};
#pragma unroll
            for (int kf = 0; kf < NKF; ++kf) {
                acc = mfma16(afl[kf], bfh[tl][kf].v, acc);
                acc = mfma16(afh[kf], bfl[tl][kf].v, acc);
                acc = mfma16(afh[kf], bfh[tl][kf].v, acc);
            }
            const int col = cw + tl * 16 + ln;
#pragma unroll
            for (int i = 0; i < 4; ++i) {
                int rowg = rbase + r * 16 + q * 4 + i;
                float val = acc[i] + bv[tl];
                if constexpr (MODE == 2) {
                    outh[rowg * 64 + col] = f2b(val * 2.0f);   // [b][s][a]
                } else if constexpr (MODE == 3) {
                    outf[rowg * N + col] = val;
                } else {
                    outf[rowg * 192 + col] = val;
                }
            }
        }
    }
}

template<int MODE, int K, int N>
__global__ __launch_bounds__(256, (MODE >= 2) ? 2 : 1) void gemm_hl(
    const float* __restrict__ srcf, const u16* __restrict__ sh,
    const u16* __restrict__ sl, const u16* __restrict__ sh2,
    const u16* __restrict__ sl2, const float* __restrict__ W,
    const float* __restrict__ bias, float* __restrict__ outf,
    u16* __restrict__ outh)
{
    gemm_body<MODE, K, N>(srcf, sh, sl, sh2, sl2, W, bias, outf, outh,
                          (int)blockIdx.x * 64);
}

// Blocks 0-3: xpv_f; 4-7: xpv_b; 8-11: xpvd; 12: decoder weight-fragment
// planes (Wd / dec_U / dec_W-ctx split-bf16, fragment layout) -> wf.
// wf u16 layout: wd_hi[0,4096) wd_lo[4096,8192) u_hi[8192,20480)
// u_lo[20480,32768) wc_hi[32768,45056) wc_lo[45056,57344).
__global__ __launch_bounds__(256, 1) void xpv_all(
    const float* __restrict__ src_emb,
    const float* __restrict__ Wf, const float* __restrict__ bf, float* __restrict__ xf,
    const float* __restrict__ Wb, const float* __restrict__ bb, float* __restrict__ xb,
    const float* __restrict__ outW, const float* __restrict__ dW,
    const float* __restrict__ db, float* __restrict__ xd,
    const float* __restrict__ dU, const float* __restrict__ Wd_,
    u16* __restrict__ wf)
{
    const int b = blockIdx.x;
    if (b < 4)
        gemm_body<0, 128, 192>(src_emb, nullptr, nullptr, nullptr, nullptr,
                               Wf, bf, xf, nullptr, b * 64);
    else if (b < 8)
        gemm_body<0, 128, 192>(src_emb, nullptr, nullptr, nullptr, nullptr,
                               Wb, bb, xb, nullptr, (b - 4) * 64);
    else if (b < 12)
        gemm_body<1, 64, 192>(outW, nullptr, nullptr, nullptr, nullptr,
                              dW, db, xd, nullptr, (b - 8) * 64);
    else {
        const int t2 = threadIdx.x;
        const int lane = t2 & 63, w2 = t2 >> 6;
        const int q = lane >> 4, ln = lane & 15;
        const int jw = w2 * 16;
#pragma unroll
        for (int kf = 0; kf < 2; ++kf)
#pragma unroll
            for (int j = 0; j < 8; ++j) {
                float f = Wd_[(kf * 32 + q * 8 + j) * 64 + jw + ln];
                u16 hi, lo; split2(f, hi, lo);
                wf[(t2 * 2 + kf) * 8 + j] = hi;
                wf[4096 + (t2 * 2 + kf) * 8 + j] = lo;
            }
#pragma unroll
        for (int g = 0; g < 3; ++g)
#pragma unroll
            for (int kf = 0; kf < 2; ++kf)
#pragma unroll
                for (int j = 0; j < 8; ++j) {
                    int k = kf * 32 + q * 8 + j, col = g * 64 + jw + ln;
                    int fi = ((t2 * 3 + g) * 2 + kf) * 8 + j;
                    u16 hi, lo;
                    split2(dU[k * 192 + col], hi, lo);
                    wf[8192 + fi] = hi;  wf[20480 + fi] = lo;
                    split2(dW[(64 + k) * 192 + col], hi, lo);
                    wf[32768 + fi] = hi; wf[45056 + fi] = lo;
                }
    }
}

// ---------------------------------------------------------------------------
// Fused bidirectional encoder GRU (split-bf16), 8 rows/block, 1024 blocks.
// ---------------------------------------------------------------------------
__global__ __launch_bounds__(256, 2) void enc8(
    const int* __restrict__ src_ids, const float* __restrict__ xf,
    const float* __restrict__ xb,
    const float* __restrict__ Uf_, const float* __restrict__ bf_,
    const float* __restrict__ Ub_, const float* __restrict__ bb_,
    u16* __restrict__ fh, u16* __restrict__ fl,
    u16* __restrict__ bh, u16* __restrict__ bl)
{
    __shared__ __attribute__((aligned(16))) u16 hsh[16 * 72];
    __shared__ __attribute__((aligned(16))) u16 hsl[16 * 72];
    const int tid  = threadIdx.x;
    const int lane = tid & 63, w = tid >> 6;
    const int q = lane >> 4, ln = lane & 15;
    const int dir = (int)(blockIdx.x >> 9);
    const int b0  = (int)(blockIdx.x & 511) * 8;
    const float* xpv = dir ? xb  : xf;
    const float* U   = dir ? Ub_ : Uf_;
    const float* b_  = dir ? bb_ : bf_;
    u16* oh = dir ? bh : fh;
    u16* ol = dir ? bl : fl;
    const int jw = w * 16;
    const bool rowok = (q < 2);

    for (int i = tid; i < 16 * 64; i += 256) {
        int r = i >> 6, c = i & 63;
        hsh[r * 72 + c] = 0; hsl[r * 72 + c] = 0;
    }
    FragU ufh[3][2], ufl[3][2];
    float b1[3];
#pragma unroll
    for (int g = 0; g < 3; ++g) {
        int col = g * 64 + jw + ln;
#pragma unroll
        for (int kf = 0; kf < 2; ++kf)
#pragma unroll
            for (int j = 0; j < 8; ++j) {
                float f = U[(kf * 32 + q * 8 + j) * 192 + col];
                split2(f, ufh[g][kf].u[j], ufl[g][kf].u[j]);
            }
        b1[g] = b_[192 + col];
    }
    float hp[4] = {0, 0, 0, 0};

    float xg[3][4];
    {
        const int s0 = dir ? 31 : 0;
#pragma unroll
        for (int i = 0; i < 4; ++i) {
            int rowv = b0 + ((q * 4 + i) & 7);
            int id = src_ids[rowv * 32 + s0];
#pragma unroll
            for (int g = 0; g < 3; ++g) xg[g][i] = xpv[id * 192 + g * 64 + jw + ln];
        }
    }
    __syncthreads();

    for (int step = 0; step < 32; ++step) {
        const int s = dir ? (31 - step) : step;
        float xgn[3][4];
        {
            int sn = dir ? (step >= 31 ? 0 : 30 - step) : (step >= 31 ? 31 : step + 1);
#pragma unroll
            for (int i = 0; i < 4; ++i) {
                int rowv = b0 + ((q * 4 + i) & 7);
                int id = src_ids[rowv * 32 + sn];
#pragma unroll
                for (int g = 0; g < 3; ++g) xgn[g][i] = xpv[id * 192 + g * 64 + jw + ln];
            }
        }
        bf16x8 a0h = load_afrag(&hsh[ln * 72 + q * 8]);
        bf16x8 a1h = load_afrag(&hsh[ln * 72 + 32 + q * 8]);
        bf16x8 a0l = load_afrag(&hsl[ln * 72 + q * 8]);
        bf16x8 a1l = load_afrag(&hsl[ln * 72 + 32 + q * 8]);
        f32x4 acc[3];
#pragma unroll
        for (int g = 0; g < 3; ++g) {
            f32x4 a = {0.f, 0.f, 0.f, 0.f};
            a = mfma16(a0l, ufh[g][0].v, a);
            a = mfma16(a0h, ufl[g][0].v, a);
            a = mfma16(a0h, ufh[g][0].v, a);
            a = mfma16(a1l, ufh[g][1].v, a);
            a = mfma16(a1h, ufl[g][1].v, a);
            a = mfma16(a1h, ufh[g][1].v, a);
            acc[g] = a;
        }
        float nh[4];
#pragma unroll
        for (int i = 0; i < 4; ++i) {
            const int rowg = b0 + q * 4 + i;
            float zz = sigm_(xg[0][i] + acc[0][i] + b1[0]);
            float rr = sigm_(xg[1][i] + acc[1][i] + b1[1]);
            float nn = tanh_(xg[2][i] + rr * (acc[2][i] + b1[2]));
            nh[i] = zz * hp[i] + (1.0f - zz) * nn;  hp[i] = nh[i];
            if (rowok) {
                const int gidx = (rowg * 32 + s) * 64 + jw + ln;
                u16 hi, lo; split2(nh[i], hi, lo);
                oh[gidx] = hi; ol[gidx] = lo;
            }
        }
        __syncthreads();
        if (rowok) {
#pragma unroll
            for (int i = 0; i < 4; ++i) {
                u16 hi, lo; split2(nh[i], hi, lo);
                hsh[(q * 4 + i) * 72 + jw + ln] = hi;
                hsl[(q * 4 + i) * 72 + jw + ln] = lo;
            }
        }
        __syncthreads();
#pragma unroll
        for (int g = 0; g < 3; ++g)
#pragma unroll
            for (int i = 0; i < 4; ++i) xg[g][i] = xgn[g][i];
    }
}

// ---------------------------------------------------------------------------
// Decoder: Bahdanau attention + GRU; 8 rows/block, 512 blocks, (256,2).
// ALL weight fragments evicted from registers: loaded per-step, per-phase
// from wf (fragment-layout planes, L1/L2-hot, fixed addresses). An opaque
// asm "+v"(zz) per step defeats LICM so the loads stay inside the loop and
// weight regs live only one phase. Peak arch demand ~110 <= the 128 cap ->
// no spill AND 2 blocks/CU (R7 proved 2-block residency at VGPR=128).
// Gates computed one at a time; z/r use a single fused 12-MFMA accumulator.
// ---------------------------------------------------------------------------
__global__ __launch_bounds__(256, 2) void dec_kernel(
    const int* __restrict__ tgt_ids, const float* __restrict__ xpvd,
    const u16* __restrict__ fh, const u16* __restrict__ fl,
    const u16* __restrict__ bh, const u16* __restrict__ bl,
    const u16* __restrict__ encpT, const u16* __restrict__ wf,
    const float* __restrict__ dec_b, const float* __restrict__ bd,
    const float* __restrict__ v_, const float* __restrict__ bv_,
    u16* __restrict__ hid_hi, u16* __restrict__ hid_lo)
{
    __shared__ __attribute__((aligned(16))) float enc_lds[8 * 2048]; // 64 KiB
    __shared__ __attribute__((aligned(16))) u16 hqh[16 * 72];
    __shared__ __attribute__((aligned(16))) u16 hql[16 * 72];
    __shared__ __attribute__((aligned(16))) u16 cxh[16 * 72];
    __shared__ __attribute__((aligned(16))) u16 cxl[16 * 72];
    __shared__ __attribute__((aligned(16))) float dpl[8 * 72];       // 2*(dproj+bd)
    __shared__ float wl[8 * 36];
    __shared__ float vl[64];
    const int tid  = threadIdx.x;
    const int lane = tid & 63, w = tid >> 6;
    const int q = lane >> 4, ln = lane & 15;
    const int b0 = blockIdx.x * 8;
    const int jw = w * 16;
    const bool rowok = (q < 2);

    // ---- stage encoded = fwd_hi+fwd_lo+bwd_hi+bwd_lo (fp32) into LDS ----
    {
        const u16* g0 = fh + (size_t)b0 * 2048;
        const u16* g1 = fl + (size_t)b0 * 2048;
        const u16* g2 = bh + (size_t)b0 * 2048;
        const u16* g3 = bl + (size_t)b0 * 2048;
        for (int i = tid; i < 8 * 2048 / 4; i += 256) {
            u16x4 v0 = *(const u16x4*)(g0 + i * 4);
            u16x4 v1 = *(const u16x4*)(g1 + i * 4);
            u16x4 v2 = *(const u16x4*)(g2 + i * 4);
            u16x4 v3 = *(const u16x4*)(g3 + i * 4);
            f32x4 f;
#pragma unroll
            for (int k = 0; k < 4; ++k)
                f[k] = (b2f(v0[k]) + b2f(v1[k])) + (b2f(v2[k]) + b2f(v3[k]));
            *(f32x4*)(&enc_lds[i * 4]) = f;
        }
    }
    if (tid < 64) vl[tid] = v_[tid];
    const float bv0 = bv_[0];

    float b1[3];
#pragma unroll
    for (int g = 0; g < 3; ++g) b1[g] = dec_b[192 + g * 64 + jw + ln];
    const float bd_ = bd[jw + ln];

    // step-invariant pointer to this thread's e-row (contiguous 64 bf16)
    const int bb2 = tid >> 5, ss = tid & 31;
    const u16* ep = &encpT[((size_t)(b0 + bb2) * 32 + ss) * 64];

    __syncthreads();   // enc_lds + vl ready

    // SVB = bias_v + sum_a v[a]   (logit = SVB - 2 * sum_a v[a]/(E+1))
    float SVB = bv0;
#pragma unroll
    for (int a = 0; a < 64; ++a) SVB += vl[a];

    // h0 = encoded[:,0]; zero-pad rows 8..15 of h and ctx tiles
    for (int i = tid; i < 16 * 64; i += 256) {
        int r = i >> 6, c = i & 63;
        if (r < 8) {
            u16 hi, lo; split2(enc_lds[r * 2048 + c], hi, lo);
            hqh[r * 72 + c] = hi; hql[r * 72 + c] = lo;
        } else {
            hqh[r * 72 + c] = 0; hql[r * 72 + c] = 0;
            cxh[r * 72 + c] = 0; cxl[r * 72 + c] = 0;
        }
    }
    float hp[4];
#pragma unroll
    for (int i = 0; i < 4; ++i)
        hp[i] = rowok ? enc_lds[(q * 4 + i) * 2048 + jw + ln] : 0.f;
    __syncthreads();

    for (int t = 0; t < 32; ++t) {
        // opaque zero: defeats LICM so weight loads stay per-step
        int zz = 0;
        asm volatile("" : "+v"(zz));
        const u16* wfp = wf + zz;

        // x-gates for this step: dec_in[t] = (t==0 ? BOW : tgt[t-1]);
        // consumed only in the final gates phase -> gather latency hidden.
        float xg[3][4];
#pragma unroll
        for (int i = 0; i < 4; ++i) {
            int rowv = b0 + ((q * 4 + i) & 7);
            int id = (t == 0) ? 1 : tgt_ids[rowv * 32 + (t - 1)];
#pragma unroll
            for (int g = 0; g < 3; ++g) xg[g][i] = xpvd[id * 192 + g * 64 + jw + ln];
        }

        bf16x8 ah0 = load_afrag(&hqh[ln * 72 + q * 8]);
        bf16x8 ah1 = load_afrag(&hqh[ln * 72 + 32 + q * 8]);
        bf16x8 al0 = load_afrag(&hql[ln * 72 + q * 8]);
        bf16x8 al1 = load_afrag(&hql[ln * 72 + 32 + q * 8]);
        // dpl = 2*(h@Wd + bd); Wd frags loaded here, live only this phase
        {
            FragU d0h, d1h, d0l, d1l;
            const u16* ph = wfp + (tid * 2) * 8;
            const u16* pl = wfp + 4096 + (tid * 2) * 8;
            d0h.q = *(const u32x4*)(ph);     d1h.q = *(const u32x4*)(ph + 8);
            d0l.q = *(const u32x4*)(pl);     d1l.q = *(const u32x4*)(pl + 8);
            f32x4 a = {0.f, 0.f, 0.f, 0.f};
            a = mfma16(al0, d0h.v, a);
            a = mfma16(ah0, d0l.v, a);
            a = mfma16(ah0, d0h.v, a);
            a = mfma16(al1, d1h.v, a);
            a = mfma16(ah1, d1l.v, a);
            a = mfma16(ah1, d1h.v, a);
            if (rowok) {
#pragma unroll
                for (int i = 0; i < 4; ++i)
                    dpl[(q * 4 + i) * 72 + jw + ln] = (a[i] + bd_) * 2.0f;
            }
        }
        __syncthreads();
        // scores + softmax over S: tanh(d+e) = 1 - 2/(exp(2d+2e)+1)
        {
            const float* dp = &dpl[bb2 * 72];
            float av0 = 0.f, av1 = 0.f, av2 = 0.f, av3 = 0.f;
#pragma unroll
            for (int a8 = 0; a8 < 8; ++a8) {
                FragU ev; ev.q = *(const u32x4*)(ep + a8 * 8);
                f32x4 d0 = *(const f32x4*)(dp + a8 * 8);
                f32x4 d1 = *(const f32x4*)(dp + a8 * 8 + 4);
#pragma unroll
                for (int j = 0; j < 8; ++j) {
                    const int a = a8 * 8 + j;
                    float u = (j < 4 ? d0[j & 3] : d1[j & 3]) + b2f(ev.u[j]);
                    float E = __expf(u);
                    float rc = vl[a] * rcp_(E + 1.0f);
                    if ((j & 3) == 0)      av0 += rc;
                    else if ((j & 3) == 1) av1 += rc;
                    else if ((j & 3) == 2) av2 += rc;
                    else                   av3 += rc;
                }
            }
            float logit = SVB - 2.0f * ((av0 + av1) + (av2 + av3));
            float m = logit;
#pragma unroll
            for (int off = 16; off > 0; off >>= 1) m = fmaxf(m, __shfl_xor(m, off, 32));
            float e2 = __expf(logit - m);
            float ssum = e2;
#pragma unroll
            for (int off = 16; off > 0; off >>= 1) ssum += __shfl_xor(ssum, off, 32);
            wl[bb2 * 36 + ss] = e2 * rcp_(ssum);
        }
        __syncthreads();
        // ctx = sum_s w[s] * encoded[b,s,:]  — LDS-only, wave-per-row sweep
#pragma unroll
        for (int rr2 = 0; rr2 < 2; ++rr2) {
            const int b = rr2 * 4 + w;
            float c0 = 0.f, c1 = 0.f, c2 = 0.f, c3 = 0.f;
#pragma unroll
            for (int s4 = 0; s4 < 8; ++s4) {
                const int s = s4 * 4 + q;
                const float ww = wl[b * 36 + s];
                f32x4 ev = *(const f32x4*)(&enc_lds[b * 2048 + s * 64 + ln * 4]);
                c0 += ww * ev[0]; c1 += ww * ev[1];
                c2 += ww * ev[2]; c3 += ww * ev[3];
            }
            c0 += __shfl_xor(c0, 16); c0 += __shfl_xor(c0, 32);
            c1 += __shfl_xor(c1, 16); c1 += __shfl_xor(c1, 32);
            c2 += __shfl_xor(c2, 16); c2 += __shfl_xor(c2, 32);
            c3 += __shfl_xor(c3, 16); c3 += __shfl_xor(c3, 32);
            if (q == 0) {
                u16x4 vh, vo;
                u16 th, tl2;
                split2(c0, th, tl2); vh[0] = th; vo[0] = tl2;
                split2(c1, th, tl2); vh[1] = th; vo[1] = tl2;
                split2(c2, th, tl2); vh[2] = th; vo[2] = tl2;
                split2(c3, th, tl2); vh[3] = th; vo[3] = tl2;
                *(u16x4*)(&cxh[b * 72 + ln * 4]) = vh;
                *(u16x4*)(&cxl[b * 72 + ln * 4]) = vo;
            }
        }
        __syncthreads();
        // GRU gates, one gate at a time (weight frags live one gate only).
        // z,r: ctx-path + rec-path accumulate into ONE acc (12 MFMAs).
        // n: paths kept separate (r multiplies only the recurrent part).
        bf16x8 ac0 = load_afrag(&cxh[ln * 72 + q * 8]);
        bf16x8 ac1 = load_afrag(&cxh[ln * 72 + 32 + q * 8]);
        bf16x8 al2 = load_afrag(&cxl[ln * 72 + q * 8]);
        bf16x8 al3 = load_afrag(&cxl[ln * 72 + 32 + q * 8]);
        f32x4 zacc, racc, axn, ahn;
#pragma unroll
        for (int g = 0; g < 3; ++g) {
            FragU u0h, u1h, u0l, u1l, c0h, c1h, c0l, c1l;
            const int fi = ((tid * 3 + g) * 2) * 8;
            const u16* uph = wfp + 8192  + fi;
            const u16* upl = wfp + 20480 + fi;
            const u16* cph = wfp + 32768 + fi;
            const u16* cpl = wfp + 45056 + fi;
            u0h.q = *(const u32x4*)(uph); u1h.q = *(const u32x4*)(uph + 8);
            u0l.q = *(const u32x4*)(upl); u1l.q = *(const u32x4*)(upl + 8);
            c0h.q = *(const u32x4*)(cph); c1h.q = *(const u32x4*)(cph + 8);
            c0l.q = *(const u32x4*)(cpl); c1l.q = *(const u32x4*)(cpl + 8);
            f32x4 a = {0.f, 0.f, 0.f, 0.f};
            a = mfma16(al2, c0h.v, a);
            a = mfma16(ac0, c0l.v, a);
            a = mfma16(ac0, c0h.v, a);
            a = mfma16(al3, c1h.v, a);
            a = mfma16(ac1, c1l.v, a);
            a = mfma16(ac1, c1h.v, a);
            if (g < 2) {
                a = mfma16(al0, u0h.v, a);
                a = mfma16(ah0, u0l.v, a);
                a = mfma16(ah0, u0h.v, a);
                a = mfma16(al1, u1h.v, a);
                a = mfma16(ah1, u1l.v, a);
                a = mfma16(ah1, u1h.v, a);
                if (g == 0) zacc = a; else racc = a;
            } else {
                axn = a;
                f32x4 h = {0.f, 0.f, 0.f, 0.f};
                h = mfma16(al0, u0h.v, h);
                h = mfma16(ah0, u0l.v, h);
                h = mfma16(ah0, u0h.v, h);
                h = mfma16(al1, u1h.v, h);
                h = mfma16(ah1, u1l.v, h);
                h = mfma16(ah1, u1h.v, h);
                ahn = h;
            }
        }
        float nh[4];
#pragma unroll
        for (int i = 0; i < 4; ++i) {
            int rowg = b0 + q * 4 + i;
            float zv = sigm_(xg[0][i] + zacc[i] + b1[0]);
            float rv = sigm_(xg[1][i] + racc[i] + b1[1]);
            float nn = tanh_(xg[2][i] + axn[i] + rv * (ahn[i] + b1[2]));
            nh[i] = zv * hp[i] + (1.0f - zv) * nn;  hp[i] = nh[i];
            if (rowok) {
                int gidx = (rowg * 32 + t) * 64 + jw + ln;
                u16 hi, lo; split2(nh[i], hi, lo);
                hid_hi[gidx] = hi; hid_lo[gidx] = lo;
                hqh[(q * 4 + i) * 72 + jw + ln] = hi;
                hql[(q * 4 + i) * 72 + jw + ln] = lo;
            }
        }
        __syncthreads();
    }
}

// ---------------------------------------------------------------------------
extern "C" void kernel_launch(void* const* d_in, const int* in_sizes, int n_in,
                              void* d_out, int out_size, void* d_ws, size_t ws_size,
                              hipStream_t stream) {
    const int*   src_ids = (const int*)d_in[0];
    const int*   tgt_ids = (const int*)d_in[1];
    const float* src_emb = (const float*)d_in[2];
    const float* enc_Wf  = (const float*)d_in[3];
    const float* enc_Uf  = (const float*)d_in[4];
    const float* enc_bf  = (const float*)d_in[5];
    const float* enc_Wb  = (const float*)d_in[6];
    const float* enc_Ub  = (const float*)d_in[7];
    const float* enc_bb  = (const float*)d_in[8];
    const float* attn_We = (const float*)d_in[9];
    const float* attn_be = (const float*)d_in[10];
    const float* attn_Wd = (const float*)d_in[11];
    const float* attn_bd = (const float*)d_in[12];
    const float* attn_v  = (const float*)d_in[13];
    const float* attn_bv = (const float*)d_in[14];
    const float* dec_W   = (const float*)d_in[15];
    const float* dec_U   = (const float*)d_in[16];
    const float* dec_b   = (const float*)d_in[17];
    const float* out_W   = (const float*)d_in[18];
    const float* out_b   = (const float*)d_in[19];

    // ws layout (u16 units). fwd [0,16)/[16,32) MiB, bwd [32,48)/[48,64),
    // encpT [64,80), xpv_f/xpv_b/xpvd, then wf (112 KB weight frags).
    u16* ws = (u16*)d_ws;
    u16* fwd_hi = ws;
    u16* fwd_lo = ws +  8388608;
    u16* bwd_hi = ws + 16777216;
    u16* bwd_lo = ws + 25165824;
    u16* encpT  = ws + 33554432;
    float* xpv_f = (float*)(ws + 41943040);
    float* xpv_b = (float*)(ws + 42041344);
    float* xpvd  = (float*)(ws + 42139648);
    u16* wf      = ws + 42237952;
    u16* hid_hi = fwd_hi;
    u16* hid_lo = fwd_lo;

    dim3 blk(256);
    xpv_all<<<13, blk, 0, stream>>>(src_emb, enc_Wf, enc_bf, xpv_f,
                                    enc_Wb, enc_bb, xpv_b,
                                    out_W, dec_W, dec_b, xpvd,
                                    dec_U, attn_Wd, wf);
    enc8<<<1024, blk, 0, stream>>>(src_ids, xpv_f, xpv_b, enc_Uf, enc_bf,
                                   enc_Ub, enc_bb, fwd_hi, fwd_lo, bwd_hi, bwd_lo);
    gemm_hl<2, 64, 64><<<2048, blk, 0, stream>>>(
        nullptr, fwd_hi, fwd_lo, bwd_hi, bwd_lo, attn_We, attn_be, nullptr, encpT);
    dec_kernel<<<512, blk, 0, stream>>>(tgt_ids, xpvd, fwd_hi, fwd_lo,
                                        bwd_hi, bwd_lo, encpT, wf,
                                        dec_b, attn_bd, attn_v, attn_bv,
                                        hid_hi, hid_lo);
    gemm_hl<3, 64, 256><<<2048, blk, 0, stream>>>(
        nullptr, hid_hi, hid_lo, nullptr, nullptr, out_W, out_b, (float*)d_out, nullptr);
}